// Round 1
// baseline (609.482 us; speedup 1.0000x reference)
//
#include <hip/hip_runtime.h>
#include <math.h>

#define N_S 256
#define T_S 20
#define D_S 32
#define NF_S 16
#define Q_S 32
#define HDYN_S 256
#define HDIM_S 1024
#define VSTEPS_S 10
#define DT_S 0.1f
#define LOG2PI_F 1.8378770664093453f

// ---- d_out offsets (floats) ----
#define OUT_XREC 0
#define OUT_QM   5242880
#define OUT_QLV  5259264
#define OUT_ZT   5275648
#define OUT_SCAL 5603328

// ---- workspace offsets (floats) ----
#define WS_A1    0
#define WS_A3    0
#define WS_WT1   0          // 32768  [tap][ci=64][co=32]
#define WS_WT2   32768      // 8192   [tap][ci=32][co=16]
#define WS_WT3   40960      // 256    [tap][ci=16]
#define WS_A2    1048576
#define WS_S0MU  1572864
#define WS_S0LV  1581056
#define WS_V0MU  1589248
#define WS_V0LV  1597440
#define WS_LOGP  1605632
#define WS_LHOOD 1610752
#define WS_KLZ   1611008
#define WS_KLW   1611264
#define WS_TC    1611520
#define TC_S1 (WS_TC + 0)
#define TC_V1 (WS_TC + 256)
#define TC_S2 (WS_TC + 2816)
#define TC_V2 (WS_TC + 11008)
#define TC_S3 (WS_TC + 19200)
#define TC_V3 (WS_TC + 51968)

// ---------------- weight transposes ----------------
__device__ inline void enc_tr(const float* __restrict__ src, float* __restrict__ dst,
                              int e, int CI, int CO) {
    int co = e % CO; int r = e / CO; int tap = r & 15; int ci = r >> 4;
    dst[e] = src[(co * CI + ci) * 16 + tap];
}
__device__ inline void dec_tr(const float* __restrict__ src, float* __restrict__ dst,
                              int e, int CI, int CO) {
    int co = e % CO; int r = e / CO; int ci = r % CI; int tap = r / CI;
    dst[e] = src[(co * CI + ci) * 16 + tap];
}

__global__ __launch_bounds__(256) void prep_enc(
    const float* __restrict__ Cs1, const float* __restrict__ Cv1,
    const float* __restrict__ Cs2, const float* __restrict__ Cv2,
    const float* __restrict__ Cs3, const float* __restrict__ Cv3,
    float* __restrict__ ws)
{
    int idx = blockIdx.x * 256 + threadIdx.x;
    if (blockIdx.x == 0) ws[WS_LHOOD + threadIdx.x] = 0.f;   // fold in lhood zeroing
    if (idx < 256)        enc_tr(Cs1, ws + TC_S1, idx,          1, 16);
    else if (idx < 2816)  enc_tr(Cv1, ws + TC_V1, idx - 256,   10, 16);
    else if (idx < 11008) enc_tr(Cs2, ws + TC_S2, idx - 2816,  16, 32);
    else if (idx < 19200) enc_tr(Cv2, ws + TC_V2, idx - 11008, 16, 32);
    else if (idx < 51968) enc_tr(Cs3, ws + TC_S3, idx - 19200, 32, 64);
    else if (idx < 84736) enc_tr(Cv3, ws + TC_V3, idx - 51968, 32, 64);
}

// ---------------- conv1: spatial-split (grid.y = yhalf); zero-padded input tile --------
template<int CIN>
__global__ __launch_bounds__(256) void conv1_lds(
    const float* __restrict__ x, const float* __restrict__ wt,
    const float* __restrict__ bias, float* __restrict__ out)
{
    __shared__ float xin[CIN * 630];   // ci*630 + r*35 + (gx+1), r = local row 0..17
    __shared__ float wl[CIN * 256];
    __shared__ float bl[16];
    int b = blockIdx.x, yh = blockIdx.y, t = threadIdx.x;
    for (int e = t; e < CIN * 576; e += 256) {
        int ci = e / 576;
        int r = (e >> 5) - ci * 18;
        int cx = e & 31;
        int gy = yh * 16 - 1 + r;
        float v = (gy >= 0 && gy < 32) ? x[(size_t)b * 20480 + ci * 1024 + gy * 32 + cx] : 0.f;
        xin[ci * 630 + r * 35 + cx + 1] = v;
    }
    for (int e = t; e < CIN * 18; e += 256) {
        int ci = e / 18, r = e - ci * 18;
        xin[ci * 630 + r * 35 + 0] = 0.f;
        xin[ci * 630 + r * 35 + 33] = 0.f;
    }
    for (int e = t; e < CIN * 256; e += 256) wl[e] = wt[e];
    if (t < 16) bl[t] = bias[t];
    __syncthreads();

    int ocq = t >> 7, p = t & 127;
    int oyl = p >> 4, ox = p & 15;
    float acc[8];
    #pragma unroll
    for (int j = 0; j < 8; j++) acc[j] = bl[ocq * 8 + j];
    for (int ci = 0; ci < CIN; ci++) {
        const float* xc = xin + ci * 630;
        const float* wc = wl + ci * 256 + ocq * 8;
        #pragma unroll
        for (int ky = 0; ky < 4; ky++) {
            const float* xr = xc + (2 * oyl + ky) * 35;
            #pragma unroll
            for (int kx = 0; kx < 4; kx++) {
                float v = xr[2 * ox + kx];     // (ix+1) = 2ox-1+kx+1
                const float4* w4 = (const float4*)(wc + (ky * 4 + kx) * 16);
                float4 wa = w4[0], wb = w4[1];
                acc[0] = fmaf(v, wa.x, acc[0]);
                acc[1] = fmaf(v, wa.y, acc[1]);
                acc[2] = fmaf(v, wa.z, acc[2]);
                acc[3] = fmaf(v, wa.w, acc[3]);
                acc[4] = fmaf(v, wb.x, acc[4]);
                acc[5] = fmaf(v, wb.y, acc[5]);
                acc[6] = fmaf(v, wb.z, acc[6]);
                acc[7] = fmaf(v, wb.w, acc[7]);
            }
        }
    }
    int oy = yh * 8 + oyl;
    size_t ob = (size_t)b * 4096 + (size_t)(ocq * 8) * 256 + oy * 16 + ox;
    #pragma unroll
    for (int j = 0; j < 8; j++) out[ob + (size_t)j * 256] = fmaxf(acc[j], 0.f);
}

// ---------------- conv2: oc-split (grid.y = half) ----------------
__global__ __launch_bounds__(256) void conv2_lds(
    const float* __restrict__ a1, const float* __restrict__ wt,  // wt: [ci][tap][32]
    const float* __restrict__ bias, float* __restrict__ out)
{
    __shared__ float xin[16 * 272];
    __shared__ float wl[4096];    // [ci][tap][16oc slice]
    __shared__ float bl[16];
    int b = blockIdx.x, h = blockIdx.y, t = threadIdx.x;
    for (int e = t; e < 4096; e += 256) {
        int ci = e >> 8, r = e & 255, iy = r >> 4, ix = r & 15;
        xin[ci * 272 + iy * 17 + ix] = a1[(size_t)b * 4096 + e];
    }
    for (int e = t; e < 4096; e += 256) {
        int ci = e >> 8, r = e & 255, tap = r >> 4, oc = r & 15;
        wl[e] = wt[ci * 512 + tap * 32 + h * 16 + oc];
    }
    if (t < 16) bl[t] = bias[h * 16 + t];
    __syncthreads();

    int ocq = t >> 6, p = t & 63;      // 4 groups x 4 oc
    int pa = p >> 3, pb = p & 7;       // oy, ox
    float acc[4];
    #pragma unroll
    for (int j = 0; j < 4; j++) acc[j] = bl[ocq * 4 + j];
    for (int ci = 0; ci < 16; ci++) {
        const float* xc = xin + ci * 272;
        const float* wc = wl + ci * 256 + ocq * 4;
        #pragma unroll
        for (int ky = 0; ky < 4; ky++) {
            int iy = 2 * pa - 1 + ky;
            if ((unsigned)iy >= 16u) continue;
            const float* xr = xc + iy * 17;
            #pragma unroll
            for (int kx = 0; kx < 4; kx++) {
                int ix = 2 * pb - 1 + kx;
                if ((unsigned)ix >= 16u) continue;
                float v = xr[ix];
                float4 wv = *(const float4*)(wc + (ky * 4 + kx) * 16);
                acc[0] = fmaf(v, wv.x, acc[0]);
                acc[1] = fmaf(v, wv.y, acc[1]);
                acc[2] = fmaf(v, wv.z, acc[2]);
                acc[3] = fmaf(v, wv.w, acc[3]);
            }
        }
    }
    size_t ob = (size_t)b * 2048 + (size_t)(h * 16 + ocq * 4) * 64 + pa * 8 + pb;
    #pragma unroll
    for (int j = 0; j < 4; j++) out[ob + (size_t)j * 64] = fmaxf(acc[j], 0.f);
}

// ---------------- conv3 (unchanged) ----------------
__global__ __launch_bounds__(256) void conv3_lds(
    const float* __restrict__ a2, const float* __restrict__ wt,
    const float* __restrict__ bias, float* __restrict__ out)
{
    __shared__ float xin[32 * 72];
    __shared__ float wl[16384];
    __shared__ float bl[32];
    int b = blockIdx.x, h = blockIdx.y, t = threadIdx.x;
    for (int e = t; e < 2048; e += 256) {
        int ci = e >> 6, r = e & 63, iy = r >> 3, ix = r & 7;
        xin[ci * 72 + iy * 9 + ix] = a2[(size_t)b * 2048 + e];
    }
    for (int e4 = t; e4 < 4096; e4 += 256) {
        int grp = e4 >> 3, c4 = e4 & 7;
        ((float4*)wl)[e4] = ((const float4*)(wt + grp * 64 + h * 32))[c4];
    }
    if (t < 32) bl[t] = bias[h * 32 + t];
    __syncthreads();

    int ocq = t >> 4, p = t & 15;
    int pa = p >> 2, pb = p & 3;
    float a0 = bl[ocq * 2], a1 = bl[ocq * 2 + 1];
    for (int ci = 0; ci < 32; ci++) {
        const float* xc = xin + ci * 72;
        const float* wc = wl + ci * 512 + ocq * 2;
        #pragma unroll
        for (int ky = 0; ky < 4; ky++) {
            int iy = 2 * pa - 1 + ky;
            if ((unsigned)iy >= 8u) continue;
            const float* xr = xc + iy * 9;
            #pragma unroll
            for (int kx = 0; kx < 4; kx++) {
                int ix = 2 * pb - 1 + kx;
                if ((unsigned)ix >= 8u) continue;
                float v = xr[ix];
                float2 wv = *(const float2*)(wc + (ky * 4 + kx) * 32);
                a0 = fmaf(v, wv.x, a0);
                a1 = fmaf(v, wv.y, a1);
            }
        }
    }
    size_t ob = (size_t)b * 1024 + (size_t)(h * 32 + ocq * 2) * 16 + pa * 4 + pb;
    out[ob] = fmaxf(a0, 0.f);
    out[ob + 16] = fmaxf(a1, 0.f);
}

// ---------------- encoder fc ----------------
__global__ __launch_bounds__(256) void fc_enc2(
    const float* __restrict__ h,
    const float* __restrict__ Wm, const float* __restrict__ bm,
    const float* __restrict__ Wl, const float* __restrict__ bl,
    float* __restrict__ mu, float* __restrict__ lv)
{
    __shared__ float pm[8][32], pl[8][32];
    int b = blockIdx.x, t = threadIdx.x;
    int q = t & 31, c = t >> 5;
    const float* hb = h + (size_t)b * HDIM_S + c * 128;
    const float* wmp = Wm + (c * 128) * Q_S + q;
    const float* wlp = Wl + (c * 128) * Q_S + q;
    float am = 0.f, al = 0.f;
    #pragma unroll 4
    for (int k = 0; k < 128; k++) {
        float hv = hb[k];
        am = fmaf(hv, wmp[k * Q_S], am);
        al = fmaf(hv, wlp[k * Q_S], al);
    }
    pm[c][q] = am; pl[c][q] = al;
    __syncthreads();
    if (t < 32) {
        float s = bm[t];
        #pragma unroll
        for (int c2 = 0; c2 < 8; c2++) s += pm[c2][t];
        mu[b * Q_S + t] = s;
    } else if (t < 64) {
        int qq = t - 32;
        float s = bl[qq];
        #pragma unroll
        for (int c2 = 0; c2 < 8; c2++) s += pl[c2][qq];
        lv[b * Q_S + qq] = s;
    }
}

// ---------------- reparameterize + decoder weight transpose (fused) ----------------
__global__ __launch_bounds__(256) void reparam_prep(
    const float* __restrict__ s0mu, const float* __restrict__ s0lv,
    const float* __restrict__ v0mu, const float* __restrict__ v0lv,
    const float* __restrict__ eps_s, const float* __restrict__ eps_v,
    const float* __restrict__ D1, const float* __restrict__ D2,
    const float* __restrict__ D3,
    float* __restrict__ ws,
    float* __restrict__ qm, float* __restrict__ qlv,
    float* __restrict__ ztL, float* __restrict__ logp)
{
    int n = blockIdx.x, t = threadIdx.x;
    int idx = n * 256 + t;
    if (idx < 32768)      dec_tr(D1, ws + WS_WT1, idx,         64, 32);
    else if (idx < 40960) dec_tr(D2, ws + WS_WT2, idx - 32768, 32, 16);
    else if (idx < 41216) dec_tr(D3, ws + WS_WT3, idx - 40960, 16, 1);
    if (t < 64) {
        int q = t & 31;
        float mu, lvv, ep;
        if (t < 32) { mu = v0mu[n*32+q]; lvv = v0lv[n*32+q]; ep = eps_v[n*32+q]; }
        else        { mu = s0mu[n*32+q]; lvv = s0lv[n*32+q]; ep = eps_s[n*32+q]; }
        float zv = fmaf(ep, expf(lvv), mu);
        qm[n*64 + t]  = mu;
        qlv[n*64 + t] = lvv;
        ztL[(size_t)n * T_S * 64 + t] = zv;
        float e2 = ep * ep;
        #pragma unroll
        for (int off = 32; off; off >>= 1) e2 += __shfl_down(e2, off, 64);
        if (t == 0) logp[n * T_S] = -0.5f * e2 - Q_S * LOG2PI_F;
    }
}

// ---------------- RK4 ODE (chain-split) ----------------
__global__ __launch_bounds__(256) void ode_kernel(
    const float* __restrict__ W1, const float* __restrict__ b1,
    const float* __restrict__ W2, const float* __restrict__ b2,
    float* __restrict__ ztL, float* __restrict__ logp)
{
    __shared__ float W2s[HDYN_S * Q_S];
    __shared__ float zeval[64];
    __shared__ float hsh[HDYN_S];
    __shared__ float dvred[HDYN_S];
    __shared__ float red4[4];
    int n = blockIdx.x;
    int t = threadIdx.x;

    for (int i = t; i < HDYN_S * Q_S; i += 256) W2s[i] = W2[i];
    float w1r[64];
    #pragma unroll
    for (int j = 0; j < 64; j++) w1r[j] = W1[j * HDYN_S + t];
    float b1r = b1[t];
    __syncthreads();
    float ck = 0.f;
    #pragma unroll
    for (int i = 0; i < Q_S; i++) ck = fmaf(w1r[i], W2s[t * Q_S + i], ck);

    size_t zoff = (size_t)n * T_S * 64;
    float zj = 0.f, ksumj = 0.f, zevalj = 0.f, lp = 0.f, lsum = 0.f;
    if (t < 64) { zj = ztL[zoff + t]; zevalj = zj; zeval[t] = zj; }
    if (t == 0) lp = logp[n * T_S];

    const float wc[4] = {1.f, 2.f, 2.f, 1.f};
    const float ac[3] = {0.5f * DT_S, 0.5f * DT_S, DT_S};

    for (int step = 1; step < T_S; step++) {
        for (int e = 0; e < 4; e++) {
            __syncthreads();
            float p0 = 0.f, p1 = 0.f, p2 = 0.f, p3 = 0.f;
            #pragma unroll
            for (int j = 0; j < 16; j++) {
                p0 = fmaf(zeval[j],      w1r[j],      p0);
                p1 = fmaf(zeval[j + 16], w1r[j + 16], p1);
                p2 = fmaf(zeval[j + 32], w1r[j + 32], p2);
                p3 = fmaf(zeval[j + 48], w1r[j + 48], p3);
            }
            float pre = b1r + ((p0 + p1) + (p2 + p3));
            float hk = tanhf(pre);
            hsh[t] = hk;
            float gk = (1.f - hk * hk) * ck;
            #pragma unroll
            for (int off = 32; off; off >>= 1) gk += __shfl_down(gk, off, 64);
            if ((t & 63) == 0) red4[t >> 6] = gk;
            __syncthreads();
            {
                int i = t & 31, p = t >> 5;
                float a0 = 0.f, a1 = 0.f;
                #pragma unroll
                for (int kk = 0; kk < 16; kk++) {
                    a0 = fmaf(hsh[p * 32 + kk],      W2s[(p * 32 + kk) * Q_S + i],      a0);
                    a1 = fmaf(hsh[p * 32 + 16 + kk], W2s[(p * 32 + 16 + kk) * Q_S + i], a1);
                }
                dvred[t] = a0 + a1;
            }
            __syncthreads();
            if (t < 64) {
                float tr = red4[0] + red4[1] + red4[2] + red4[3];
                float zv_shfl = __shfl(zevalj, (t >= 32) ? (t - 32) : t, 64);
                float kzv;
                if (t < 32) {
                    float dvi = b2[t];
                    #pragma unroll
                    for (int p = 0; p < 8; p++) dvi += dvred[p * 32 + t];
                    kzv = dvi;
                } else kzv = zv_shfl;
                if (e == 0) ksumj = kzv; else ksumj = fmaf(wc[e], kzv, ksumj);
                if (t == 0) { float kl = -tr; lsum = (e == 0) ? kl : fmaf(wc[e], kl, lsum); }
                if (e < 3) {
                    zevalj = fmaf(ac[e], kzv, zj);
                    zeval[t] = zevalj;
                } else {
                    zj = fmaf(DT_S / 6.f, ksumj, zj);
                    zevalj = zj; zeval[t] = zj;
                    ztL[zoff + step * 64 + t] = zj;
                    if (t == 0) { lp = fmaf(DT_S / 6.f, lsum, lp); logp[n * T_S + step] = lp; }
                }
            }
        }
    }
}

// ---------------- fused decoder v6: compact bank-uniform LDS (31.2 KB -> 5 blocks/CU) ----
// Region B (regB, 4160 f):
//   slp : zero-padded [iy+1:0..5]*452 + [ix+1:0..5]*72 + ci(0..63)
//         452%32=4, 72%32=8 -> deconv1's 8 broadcast f4 addrs hit bases {0,4,..,28}: conflict-free
//   h2f : full [16][16] pos, ci stride 16, row stride 260 (260%32=4)
//         deconv3 read bank = 4*iy+16*ix -> uniform 8 accesses/bank
// Region A (regA, 3600 f):
//   h1f : full zero-padded [y+1:0..9]*360 + [x+1:0..9]*36 + oc(0..31)
//         360%32=8, 36%32=4 -> deconv2 read bank = 8*iyf+4*ixf -> uniform (and no parity math)
//   xst : 32 rows * 36 (aliased after h1f dead)
__global__ __launch_bounds__(256) void decoder5(
    const float* __restrict__ ztL, const float* __restrict__ Wf, const float* __restrict__ bf,
    const float* __restrict__ wt1, const float* __restrict__ d1,
    const float* __restrict__ wt2, const float* __restrict__ d2,
    const float* __restrict__ wt3, const float* __restrict__ d3,
    const float* __restrict__ X, float* __restrict__ Xrec, float* __restrict__ lhood)
{
    __shared__ float zs[32];
    __shared__ float regA[3600];
    __shared__ float regB[4160];
    __shared__ float sh4[4];
    float* slp = regB;
    float* h2f = regB;
    float* h1f = regA;
    float* xst = regA;
    const int bidx = blockIdx.x;
    const int t = threadIdx.x;
    const int wu = __builtin_amdgcn_readfirstlane(t >> 6);   // wave id, provably uniform
    const int l = t & 63;
    const int py = wu >> 1, px = wu & 1;

    // ---- P0: zero padded LDS + load z ----
    if (t < 32) zs[t] = ztL[(size_t)bidx * 64 + 32 + t];
    {
        float4 z4 = make_float4(0.f, 0.f, 0.f, 0.f);
        for (int e = t; e < 678; e += 256) ((float4*)regB)[e] = z4;   // slp extent 2712 f
        for (int e = t; e < 900; e += 256) ((float4*)regA)[e] = z4;   // h1f extent 3600 f
    }
    __syncthreads();

    // ---- fc3: s = z_s @ Wf + bf -> slp ----
    {
        float4 acc = ((const float4*)bf)[t];
        const float4* Wf4 = (const float4*)Wf;
        #pragma unroll 4
        for (int q = 0; q < 32; q++) {
            float zq = zs[q];
            float4 wv = Wf4[q * 256 + t];
            acc.x = fmaf(zq, wv.x, acc.x);
            acc.y = fmaf(zq, wv.y, acc.y);
            acc.z = fmaf(zq, wv.z, acc.z);
            acc.w = fmaf(zq, wv.w, acc.w);
        }
        int k0 = t * 4;
        int ci = k0 >> 4;
        int iy = t & 3;               // p0 = 4*(t&3)+j -> row = t&3, col = j
        float vv[4] = {acc.x, acc.y, acc.z, acc.w};
        #pragma unroll
        for (int j = 0; j < 4; j++)
            slp[(iy + 1) * 452 + (j + 1) * 72 + ci] = vv[j];
    }
    __syncthreads();

    // ---- deconv1: [4,4,64] -> full h1 [8,8,32]; thread = 2pos x 4oc ----
    {
        int ocq = l >> 3;
        int pp = l & 7;
        int a_ = pp >> 1, b2 = pp & 1;
        float acc0[4], acc1[4];
        #pragma unroll
        for (int j = 0; j < 4; j++) { acc0[j] = d1[ocq * 4 + j]; acc1[j] = acc0[j]; }
        #pragma unroll
        for (int sy = 0; sy < 2; sy++) {
            int ky = py + 2 * sy;
            int iy = a_ + py + sy - 1;          // -1..4, pad covers
            #pragma unroll
            for (int sx = 0; sx < 2; sx++) {
                int kx = px + 2 * sx;
                int ix0 = 2 * b2 + px + sx - 1; // -1..3
                const float4* ip0 = (const float4*)(slp + (iy + 1) * 452 + (ix0 + 1) * 72);
                const float4* ip1 = (const float4*)((const float*)ip0 + 72);
                const float* wb = wt1 + (ky * 4 + kx) * 2048 + ocq * 4;
                #pragma unroll 4
                for (int cc = 0; cc < 16; cc++) {
                    float4 va = ip0[cc];
                    float4 vb = ip1[cc];
                    float av[4] = {va.x, va.y, va.z, va.w};
                    float bv[4] = {vb.x, vb.y, vb.z, vb.w};
                    #pragma unroll
                    for (int r = 0; r < 4; r++) {
                        float4 wv = *(const float4*)(wb + (cc * 4 + r) * 32);
                        acc0[0] = fmaf(av[r], wv.x, acc0[0]); acc1[0] = fmaf(bv[r], wv.x, acc1[0]);
                        acc0[1] = fmaf(av[r], wv.y, acc0[1]); acc1[1] = fmaf(bv[r], wv.y, acc1[1]);
                        acc0[2] = fmaf(av[r], wv.z, acc0[2]); acc1[2] = fmaf(bv[r], wv.z, acc1[2]);
                        acc0[3] = fmaf(av[r], wv.w, acc0[3]); acc1[3] = fmaf(bv[r], wv.w, acc1[3]);
                    }
                }
            }
        }
        // full coords: y = 2*a_ + py ; x = 2*ox + px  (ox0 = 2*b2, ox1 = 2*b2+1)
        int y = 2 * a_ + py;
        int x0 = 4 * b2 + px;
        float4 r0, r1;
        r0.x = fmaxf(acc0[0],0.f); r0.y = fmaxf(acc0[1],0.f); r0.z = fmaxf(acc0[2],0.f); r0.w = fmaxf(acc0[3],0.f);
        r1.x = fmaxf(acc1[0],0.f); r1.y = fmaxf(acc1[1],0.f); r1.z = fmaxf(acc1[2],0.f); r1.w = fmaxf(acc1[3],0.f);
        *(float4*)(h1f + (y + 1) * 360 + (x0 + 1) * 36 + ocq * 4) = r0;
        *(float4*)(h1f + (y + 1) * 360 + (x0 + 3) * 36 + ocq * 4) = r1;
    }
    __syncthreads();

    // ---- deconv2: thread = 1 pos x ALL 16 oc; weights fully wave-uniform (s_load) ----
    {
        int a = l >> 3, b = l & 7;     // output pos2 in plane (py,px)
        float acc[16];
        #pragma unroll
        for (int j = 0; j < 16; j++) acc[j] = d2[j];
        #pragma unroll
        for (int sy = 0; sy < 2; sy++) {
            int ky = py + 2 * sy;
            int iyf = a + py + sy - 1;          // -1..8, pad covers
            #pragma unroll
            for (int sx = 0; sx < 2; sx++) {
                int kx = px + 2 * sx;
                int ixf = b + px + sx - 1;
                const float4* ip4 = (const float4*)(h1f + (iyf + 1) * 360 + (ixf + 1) * 36);
                const float* wb = wt2 + (ky * 4 + kx) * 512;   // uniform
                #pragma unroll 2
                for (int cc = 0; cc < 8; cc++) {
                    float4 v = ip4[cc];
                    float vv[4] = {v.x, v.y, v.z, v.w};
                    #pragma unroll
                    for (int r = 0; r < 4; r++) {
                        const float4* wq = (const float4*)(wb + (cc * 4 + r) * 16);
                        float4 w0 = wq[0], w1 = wq[1], w2 = wq[2], w3 = wq[3];
                        float vr = vv[r];
                        acc[0]  = fmaf(vr, w0.x, acc[0]);
                        acc[1]  = fmaf(vr, w0.y, acc[1]);
                        acc[2]  = fmaf(vr, w0.z, acc[2]);
                        acc[3]  = fmaf(vr, w0.w, acc[3]);
                        acc[4]  = fmaf(vr, w1.x, acc[4]);
                        acc[5]  = fmaf(vr, w1.y, acc[5]);
                        acc[6]  = fmaf(vr, w1.z, acc[6]);
                        acc[7]  = fmaf(vr, w1.w, acc[7]);
                        acc[8]  = fmaf(vr, w2.x, acc[8]);
                        acc[9]  = fmaf(vr, w2.y, acc[9]);
                        acc[10] = fmaf(vr, w2.z, acc[10]);
                        acc[11] = fmaf(vr, w2.w, acc[11]);
                        acc[12] = fmaf(vr, w3.x, acc[12]);
                        acc[13] = fmaf(vr, w3.y, acc[13]);
                        acc[14] = fmaf(vr, w3.z, acc[14]);
                        acc[15] = fmaf(vr, w3.w, acc[15]);
                    }
                }
            }
        }
        __syncthreads();   // slp (aliased with h2f) reads fully done block-wide
        // full coords: y = 2a+py, x = 2b+px; ci contiguous stride 16, row stride 260
        float* hq = h2f + (2 * a + py) * 260 + (2 * b + px) * 16;
        #pragma unroll
        for (int j = 0; j < 4; j++) {
            float4 r;
            r.x = fmaxf(acc[j*4+0], 0.f);
            r.y = fmaxf(acc[j*4+1], 0.f);
            r.z = fmaxf(acc[j*4+2], 0.f);
            r.w = fmaxf(acc[j*4+3], 0.f);
            *(float4*)(hq + j * 4) = r;
        }
    }
    __syncthreads();

    // ---- deconv3: full [16,16,16] -> [32,32]; weights via uniform s_load ----
    {
        int oy2 = l >> 2, b3 = l & 3;
        float acc[4];
        float d30 = d3[0];
        #pragma unroll
        for (int k = 0; k < 4; k++) acc[k] = d30;
        #pragma unroll
        for (int sy = 0; sy < 2; sy++) {
            int ky = py + 2 * sy;
            int iy = oy2 + py + sy - 1;
            if ((unsigned)iy >= 16u) continue;
            #pragma unroll
            for (int sx = 0; sx < 2; sx++) {
                int kx = px + 2 * sx;
                int cx = px + sx - 1;
                const float* wvp = wt3 + (ky * 4 + kx) * 16;   // uniform
                #pragma unroll
                for (int k = 0; k < 4; k++) {
                    int ix = b3 + 4 * k + cx;
                    if ((unsigned)ix >= 16u) continue;
                    const float4* in4 = (const float4*)(h2f + iy * 260 + ix * 16);
                    #pragma unroll
                    for (int cc = 0; cc < 4; cc++) {
                        float4 v = in4[cc];
                        float4 wq = ((const float4*)wvp)[cc];
                        acc[k] = fmaf(v.x, wq.x, acc[k]);
                        acc[k] = fmaf(v.y, wq.y, acc[k]);
                        acc[k] = fmaf(v.z, wq.z, acc[k]);
                        acc[k] = fmaf(v.w, wq.w, acc[k]);
                    }
                }
            }
        }
        int oy = 2 * oy2 + py;
        #pragma unroll
        for (int k = 0; k < 4; k++) {
            int ox = 2 * (b3 + 4 * k) + px;
            xst[oy * 36 + ox] = 1.f / (1.f + expf(-acc[k]));
        }
    }
    __syncthreads();

    // ---- coalesced Xrec write + X read + lhood ----
    {
        int row = t >> 3, col = (t & 7) * 4;
        float4 xr4 = *(const float4*)(xst + row * 36 + col);
        *(float4*)(Xrec + (size_t)bidx * 1024 + t * 4) = xr4;
        float4 xi4 = *(const float4*)(X + (size_t)bidx * 1024 + t * 4);
        float ll = 0.f;
        ll += logf(0.001f + xr4.x) * xi4.x + logf(1.001f - xr4.x) * (1.f - xi4.x);
        ll += logf(0.001f + xr4.y) * xi4.y + logf(1.001f - xr4.y) * (1.f - xi4.y);
        ll += logf(0.001f + xr4.z) * xi4.z + logf(1.001f - xr4.z) * (1.f - xi4.z);
        ll += logf(0.001f + xr4.w) * xi4.w + logf(1.001f - xr4.w) * (1.f - xi4.w);
        #pragma unroll
        for (int off = 32; off; off >>= 1) ll += __shfl_down(ll, off, 64);
        if ((t & 63) == 0) sh4[t >> 6] = ll;
    }
    __syncthreads();
    if (t == 0) atomicAdd(&lhood[bidx / T_S], sh4[0] + sh4[1] + sh4[2] + sh4[3]);
}

// ---------------- kl_z ----------------
__global__ __launch_bounds__(64) void klz_kernel(
    const float* __restrict__ ztL, const float* __restrict__ logp, float* __restrict__ klz)
{
    int n = blockIdx.x, t = threadIdx.x;
    float v = 0.f;
    if (t < T_S) {
        const float* z = ztL + ((size_t)n * T_S + t) * 64;
        float s2 = 0.f;
        #pragma unroll
        for (int j = 0; j < 64; j++) s2 = fmaf(z[j], z[j], s2);
        v = logp[n * T_S + t] - (-0.5f * s2 - Q_S * LOG2PI_F);
    }
    #pragma unroll
    for (int off = 32; off; off >>= 1) v += __shfl_down(v, off, 64);
    if (t == 0) klz[n] = v;
}

// ---------------- final scalars (+ kl_w fused) ----------------
__global__ __launch_bounds__(256) void final2(
    const float* __restrict__ lhood, const float* __restrict__ klz,
    const float* __restrict__ W1, const float* __restrict__ W2,
    const int* __restrict__ Ndata, float* __restrict__ outs)
{
    __shared__ float shA[4], shB[4], shC[4];
    int t = threadIdx.x;
    float a = lhood[t];
    float b = klz[t];
    float c = 0.f;
    for (int i = t; i < 64 * HDYN_S; i += 256) c = fmaf(W1[i], W1[i], c);
    for (int i = t; i < HDYN_S * Q_S; i += 256) c = fmaf(W2[i], W2[i], c);
    #pragma unroll
    for (int off = 32; off; off >>= 1) {
        a += __shfl_down(a, off, 64);
        b += __shfl_down(b, off, 64);
        c += __shfl_down(c, off, 64);
    }
    if ((t & 63) == 0) { shA[t >> 6] = a; shB[t >> 6] = b; shC[t >> 6] = c; }
    __syncthreads();
    if (t == 0) {
        float Nd = (float)Ndata[0];
        float lh = Nd * ((shA[0] + shA[1] + shA[2] + shA[3]) / 256.f);
        float kz = Nd * ((shB[0] + shB[1] + shB[2] + shB[3]) / 256.f);
        float bkw = 0.5f * (shC[0] + shC[1] + shC[2] + shC[3]);
        outs[0] = lh - kz - bkw;
        outs[1] = lh;
        outs[2] = kz;
        outs[3] = bkw;
    }
}

extern "C" void kernel_launch(void* const* d_in, const int* in_sizes, int n_in,
                              void* d_out, int out_size, void* d_ws, size_t ws_size,
                              hipStream_t stream) {
    const float* X      = (const float*)d_in[0];
    const float* eps_s0 = (const float*)d_in[1];
    const float* eps_v0 = (const float*)d_in[2];
    const float* Cs1 = (const float*)d_in[3],  *cs1 = (const float*)d_in[4];
    const float* Cs2 = (const float*)d_in[5],  *cs2 = (const float*)d_in[6];
    const float* Cs3 = (const float*)d_in[7],  *cs3 = (const float*)d_in[8];
    const float* Wsm = (const float*)d_in[9],  *bsm = (const float*)d_in[10];
    const float* Wsl = (const float*)d_in[11], *bsl = (const float*)d_in[12];
    const float* Cv1 = (const float*)d_in[13], *cv1 = (const float*)d_in[14];
    const float* Cv2 = (const float*)d_in[15], *cv2 = (const float*)d_in[16];
    const float* Cv3 = (const float*)d_in[17], *cv3 = (const float*)d_in[18];
    const float* Wvm = (const float*)d_in[19], *bvm = (const float*)d_in[20];
    const float* Wvl = (const float*)d_in[21], *bvl = (const float*)d_in[22];
    const float* W1  = (const float*)d_in[23], *b1  = (const float*)d_in[24];
    const float* W2  = (const float*)d_in[25], *b2  = (const float*)d_in[26];
    const float* Wf  = (const float*)d_in[27], *bf  = (const float*)d_in[28];
    const float* D1  = (const float*)d_in[29], *d1  = (const float*)d_in[30];
    const float* D2  = (const float*)d_in[31], *d2  = (const float*)d_in[32];
    const float* D3  = (const float*)d_in[33], *d3  = (const float*)d_in[34];
    const int*   Ndata = (const int*)d_in[35];

    float* out = (float*)d_out;
    float* ws  = (float*)d_ws;

    prep_enc<<<331, 256, 0, stream>>>(Cs1, Cv1, Cs2, Cv2, Cs3, Cv3, ws);

    // ---- encoder s (frame 0) ----
    conv1_lds<1><<<dim3(256, 2), 256, 0, stream>>>(X, ws + TC_S1, cs1, ws + WS_A1);
    conv2_lds<<<dim3(256, 2), 256, 0, stream>>>(ws + WS_A1, ws + TC_S2, cs2, ws + WS_A2);
    conv3_lds<<<dim3(256, 2), 256, 0, stream>>>(ws + WS_A2, ws + TC_S3, cs3, ws + WS_A3);
    fc_enc2<<<256, 256, 0, stream>>>(ws + WS_A3, Wsm, bsm, Wsl, bsl, ws + WS_S0MU, ws + WS_S0LV);

    // ---- encoder v (10 frames as channels) ----
    conv1_lds<10><<<dim3(256, 2), 256, 0, stream>>>(X, ws + TC_V1, cv1, ws + WS_A1);
    conv2_lds<<<dim3(256, 2), 256, 0, stream>>>(ws + WS_A1, ws + TC_V2, cv2, ws + WS_A2);
    conv3_lds<<<dim3(256, 2), 256, 0, stream>>>(ws + WS_A2, ws + TC_V3, cv3, ws + WS_A3);
    fc_enc2<<<256, 256, 0, stream>>>(ws + WS_A3, Wvm, bvm, Wvl, bvl, ws + WS_V0MU, ws + WS_V0LV);

    // ---- reparameterize + decoder weight transpose (A-regions now dead) ----
    reparam_prep<<<256, 256, 0, stream>>>(ws + WS_S0MU, ws + WS_S0LV, ws + WS_V0MU, ws + WS_V0LV,
                                          eps_s0, eps_v0, D1, D2, D3, ws,
                                          out + OUT_QM, out + OUT_QLV,
                                          out + OUT_ZT, ws + WS_LOGP);

    // ---- RK4 ODE ----
    ode_kernel<<<256, 256, 0, stream>>>(W1, b1, W2, b2, out + OUT_ZT, ws + WS_LOGP);

    // ---- fused decoder ----
    decoder5<<<5120, 256, 0, stream>>>(out + OUT_ZT, Wf, bf,
                                       ws + WS_WT1, d1, ws + WS_WT2, d2, ws + WS_WT3, d3,
                                       X, out + OUT_XREC, ws + WS_LHOOD);

    // ---- ELBO pieces ----
    klz_kernel<<<256, 64, 0, stream>>>(out + OUT_ZT, ws + WS_LOGP, ws + WS_KLZ);
    final2<<<1, 256, 0, stream>>>(ws + WS_LHOOD, ws + WS_KLZ, W1, W2, Ndata,
                                  out + OUT_SCAL);
}

// Round 2
// 502.375 us; speedup vs baseline: 1.2132x; 1.2132x over previous
//
#include <hip/hip_runtime.h>
#include <math.h>

#define N_S 256
#define T_S 20
#define D_S 32
#define NF_S 16
#define Q_S 32
#define HDYN_S 256
#define HDIM_S 1024
#define VSTEPS_S 10
#define DT_S 0.1f
#define LOG2PI_F 1.8378770664093453f

// ---- d_out offsets (floats) ----
#define OUT_XREC 0
#define OUT_QM   5242880
#define OUT_QLV  5259264
#define OUT_ZT   5275648
#define OUT_SCAL 5603328

// ---- workspace offsets (floats) ----
#define WS_A1    0
#define WS_A3    0
#define WS_WT2   32768      // 8192   [tap][ci=32][co=16]
#define WS_WT3   40960      // 256    [tap][ci=16]
#define WS_A2    1048576
#define WS_M1    1048576    // 65536: M1L[(j*8+q4)*256 + t] float4 (composed fc3+deconv1)
#define WS_C1    1114112    // 2048:  c1L[j*256 + t]
#define WS_S0MU  1572864
#define WS_S0LV  1581056
#define WS_V0MU  1589248
#define WS_V0LV  1597440
#define WS_LOGP  1605632
#define WS_LHOOD 1610752
#define WS_KLZ   1611008
#define WS_KLW   1611264
#define WS_TC    1611520
#define TC_S1 (WS_TC + 0)
#define TC_V1 (WS_TC + 256)
#define TC_S2 (WS_TC + 2816)
#define TC_V2 (WS_TC + 11008)
#define TC_S3 (WS_TC + 19200)
#define TC_V3 (WS_TC + 51968)

// ---------------- weight transposes ----------------
__device__ inline void enc_tr(const float* __restrict__ src, float* __restrict__ dst,
                              int e, int CI, int CO) {
    int co = e % CO; int r = e / CO; int tap = r & 15; int ci = r >> 4;
    dst[e] = src[(co * CI + ci) * 16 + tap];
}
__device__ inline void dec_tr(const float* __restrict__ src, float* __restrict__ dst,
                              int e, int CI, int CO) {
    int co = e % CO; int r = e / CO; int ci = r % CI; int tap = r / CI;
    dst[e] = src[(co * CI + ci) * 16 + tap];
}

__global__ __launch_bounds__(256) void prep_enc(
    const float* __restrict__ Cs1, const float* __restrict__ Cv1,
    const float* __restrict__ Cs2, const float* __restrict__ Cv2,
    const float* __restrict__ Cs3, const float* __restrict__ Cv3,
    float* __restrict__ ws)
{
    int idx = blockIdx.x * 256 + threadIdx.x;
    if (blockIdx.x == 0) ws[WS_LHOOD + threadIdx.x] = 0.f;   // fold in lhood zeroing
    if (idx < 256)        enc_tr(Cs1, ws + TC_S1, idx,          1, 16);
    else if (idx < 2816)  enc_tr(Cv1, ws + TC_V1, idx - 256,   10, 16);
    else if (idx < 11008) enc_tr(Cs2, ws + TC_S2, idx - 2816,  16, 32);
    else if (idx < 19200) enc_tr(Cv2, ws + TC_V2, idx - 11008, 16, 32);
    else if (idx < 51968) enc_tr(Cs3, ws + TC_S3, idx - 19200, 32, 64);
    else if (idx < 84736) enc_tr(Cv3, ws + TC_V3, idx - 51968, 32, 64);
}

// ---------------- conv1: spatial-split (grid.y = yhalf); zero-padded input tile --------
template<int CIN>
__global__ __launch_bounds__(256) void conv1_lds(
    const float* __restrict__ x, const float* __restrict__ wt,
    const float* __restrict__ bias, float* __restrict__ out)
{
    __shared__ float xin[CIN * 630];   // ci*630 + r*35 + (gx+1), r = local row 0..17
    __shared__ float wl[CIN * 256];
    __shared__ float bl[16];
    int b = blockIdx.x, yh = blockIdx.y, t = threadIdx.x;
    for (int e = t; e < CIN * 576; e += 256) {
        int ci = e / 576;
        int r = (e >> 5) - ci * 18;
        int cx = e & 31;
        int gy = yh * 16 - 1 + r;
        float v = (gy >= 0 && gy < 32) ? x[(size_t)b * 20480 + ci * 1024 + gy * 32 + cx] : 0.f;
        xin[ci * 630 + r * 35 + cx + 1] = v;
    }
    for (int e = t; e < CIN * 18; e += 256) {
        int ci = e / 18, r = e - ci * 18;
        xin[ci * 630 + r * 35 + 0] = 0.f;
        xin[ci * 630 + r * 35 + 33] = 0.f;
    }
    for (int e = t; e < CIN * 256; e += 256) wl[e] = wt[e];
    if (t < 16) bl[t] = bias[t];
    __syncthreads();

    int ocq = t >> 7, p = t & 127;
    int oyl = p >> 4, ox = p & 15;
    float acc[8];
    #pragma unroll
    for (int j = 0; j < 8; j++) acc[j] = bl[ocq * 8 + j];
    for (int ci = 0; ci < CIN; ci++) {
        const float* xc = xin + ci * 630;
        const float* wc = wl + ci * 256 + ocq * 8;
        #pragma unroll
        for (int ky = 0; ky < 4; ky++) {
            const float* xr = xc + (2 * oyl + ky) * 35;
            #pragma unroll
            for (int kx = 0; kx < 4; kx++) {
                float v = xr[2 * ox + kx];     // (ix+1) = 2ox-1+kx+1
                const float4* w4 = (const float4*)(wc + (ky * 4 + kx) * 16);
                float4 wa = w4[0], wb = w4[1];
                acc[0] = fmaf(v, wa.x, acc[0]);
                acc[1] = fmaf(v, wa.y, acc[1]);
                acc[2] = fmaf(v, wa.z, acc[2]);
                acc[3] = fmaf(v, wa.w, acc[3]);
                acc[4] = fmaf(v, wb.x, acc[4]);
                acc[5] = fmaf(v, wb.y, acc[5]);
                acc[6] = fmaf(v, wb.z, acc[6]);
                acc[7] = fmaf(v, wb.w, acc[7]);
            }
        }
    }
    int oy = yh * 8 + oyl;
    size_t ob = (size_t)b * 4096 + (size_t)(ocq * 8) * 256 + oy * 16 + ox;
    #pragma unroll
    for (int j = 0; j < 8; j++) out[ob + (size_t)j * 256] = fmaxf(acc[j], 0.f);
}

// ---------------- conv2: oc-split (grid.y = half) ----------------
__global__ __launch_bounds__(256) void conv2_lds(
    const float* __restrict__ a1, const float* __restrict__ wt,  // wt: [ci][tap][32]
    const float* __restrict__ bias, float* __restrict__ out)
{
    __shared__ float xin[16 * 272];
    __shared__ float wl[4096];    // [ci][tap][16oc slice]
    __shared__ float bl[16];
    int b = blockIdx.x, h = blockIdx.y, t = threadIdx.x;
    for (int e = t; e < 4096; e += 256) {
        int ci = e >> 8, r = e & 255, iy = r >> 4, ix = r & 15;
        xin[ci * 272 + iy * 17 + ix] = a1[(size_t)b * 4096 + e];
    }
    for (int e = t; e < 4096; e += 256) {
        int ci = e >> 8, r = e & 255, tap = r >> 4, oc = r & 15;
        wl[e] = wt[ci * 512 + tap * 32 + h * 16 + oc];
    }
    if (t < 16) bl[t] = bias[h * 16 + t];
    __syncthreads();

    int ocq = t >> 6, p = t & 63;      // 4 groups x 4 oc
    int pa = p >> 3, pb = p & 7;       // oy, ox
    float acc[4];
    #pragma unroll
    for (int j = 0; j < 4; j++) acc[j] = bl[ocq * 4 + j];
    for (int ci = 0; ci < 16; ci++) {
        const float* xc = xin + ci * 272;
        const float* wc = wl + ci * 256 + ocq * 4;
        #pragma unroll
        for (int ky = 0; ky < 4; ky++) {
            int iy = 2 * pa - 1 + ky;
            if ((unsigned)iy >= 16u) continue;
            const float* xr = xc + iy * 17;
            #pragma unroll
            for (int kx = 0; kx < 4; kx++) {
                int ix = 2 * pb - 1 + kx;
                if ((unsigned)ix >= 16u) continue;
                float v = xr[ix];
                float4 wv = *(const float4*)(wc + (ky * 4 + kx) * 16);
                acc[0] = fmaf(v, wv.x, acc[0]);
                acc[1] = fmaf(v, wv.y, acc[1]);
                acc[2] = fmaf(v, wv.z, acc[2]);
                acc[3] = fmaf(v, wv.w, acc[3]);
            }
        }
    }
    size_t ob = (size_t)b * 2048 + (size_t)(h * 16 + ocq * 4) * 64 + pa * 8 + pb;
    #pragma unroll
    for (int j = 0; j < 4; j++) out[ob + (size_t)j * 64] = fmaxf(acc[j], 0.f);
}

// ---------------- conv3 (unchanged) ----------------
__global__ __launch_bounds__(256) void conv3_lds(
    const float* __restrict__ a2, const float* __restrict__ wt,
    const float* __restrict__ bias, float* __restrict__ out)
{
    __shared__ float xin[32 * 72];
    __shared__ float wl[16384];
    __shared__ float bl[32];
    int b = blockIdx.x, h = blockIdx.y, t = threadIdx.x;
    for (int e = t; e < 2048; e += 256) {
        int ci = e >> 6, r = e & 63, iy = r >> 3, ix = r & 7;
        xin[ci * 72 + iy * 9 + ix] = a2[(size_t)b * 2048 + e];
    }
    for (int e4 = t; e4 < 4096; e4 += 256) {
        int grp = e4 >> 3, c4 = e4 & 7;
        ((float4*)wl)[e4] = ((const float4*)(wt + grp * 64 + h * 32))[c4];
    }
    if (t < 32) bl[t] = bias[h * 32 + t];
    __syncthreads();

    int ocq = t >> 4, p = t & 15;
    int pa = p >> 2, pb = p & 3;
    float a0 = bl[ocq * 2], a1 = bl[ocq * 2 + 1];
    for (int ci = 0; ci < 32; ci++) {
        const float* xc = xin + ci * 72;
        const float* wc = wl + ci * 512 + ocq * 2;
        #pragma unroll
        for (int ky = 0; ky < 4; ky++) {
            int iy = 2 * pa - 1 + ky;
            if ((unsigned)iy >= 8u) continue;
            const float* xr = xc + iy * 9;
            #pragma unroll
            for (int kx = 0; kx < 4; kx++) {
                int ix = 2 * pb - 1 + kx;
                if ((unsigned)ix >= 8u) continue;
                float v = xr[ix];
                float2 wv = *(const float2*)(wc + (ky * 4 + kx) * 32);
                a0 = fmaf(v, wv.x, a0);
                a1 = fmaf(v, wv.y, a1);
            }
        }
    }
    size_t ob = (size_t)b * 1024 + (size_t)(h * 32 + ocq * 2) * 16 + pa * 4 + pb;
    out[ob] = fmaxf(a0, 0.f);
    out[ob + 16] = fmaxf(a1, 0.f);
}

// ---------------- encoder fc ----------------
__global__ __launch_bounds__(256) void fc_enc2(
    const float* __restrict__ h,
    const float* __restrict__ Wm, const float* __restrict__ bm,
    const float* __restrict__ Wl, const float* __restrict__ bl,
    float* __restrict__ mu, float* __restrict__ lv)
{
    __shared__ float pm[8][32], pl[8][32];
    int b = blockIdx.x, t = threadIdx.x;
    int q = t & 31, c = t >> 5;
    const float* hb = h + (size_t)b * HDIM_S + c * 128;
    const float* wmp = Wm + (c * 128) * Q_S + q;
    const float* wlp = Wl + (c * 128) * Q_S + q;
    float am = 0.f, al = 0.f;
    #pragma unroll 4
    for (int k = 0; k < 128; k++) {
        float hv = hb[k];
        am = fmaf(hv, wmp[k * Q_S], am);
        al = fmaf(hv, wlp[k * Q_S], al);
    }
    pm[c][q] = am; pl[c][q] = al;
    __syncthreads();
    if (t < 32) {
        float s = bm[t];
        #pragma unroll
        for (int c2 = 0; c2 < 8; c2++) s += pm[c2][t];
        mu[b * Q_S + t] = s;
    } else if (t < 64) {
        int qq = t - 32;
        float s = bl[qq];
        #pragma unroll
        for (int c2 = 0; c2 < 8; c2++) s += pl[c2][qq];
        lv[b * Q_S + qq] = s;
    }
}

// ---------------- m1_prep: compose fc3+deconv1 into M1 (2048x32) + c1 (2048) ----------
// M1[(y,x,oc)][q] = sum_{ky=y&1+2sy, kx=x&1+2sx; 0<=iy,ix<4} Wf[q][ci*16+iy*4+ix]
//                   * D1[oc*1024 + ci*16 + ky*4+kx],  iy=(y+ky)/2-1, ix=(x+kx)/2-1
// Layout: M1L f4 index (j*8+q4)*256 + t, components qq (q = q4*4+qq);
//         thread map t: p = t&63 (y=p>>3, x=p&7), ocg = t>>6, oc = ocg*8+j.
// c1L[j*256 + ocg*64 + p] = d1[oc] + same-sum with bf.
__global__ __launch_bounds__(256) void m1_prep(
    const float* __restrict__ Wf, const float* __restrict__ bf,
    const float* __restrict__ D1, const float* __restrict__ d1,
    float* __restrict__ ws)
{
    int blk = blockIdx.x, t = threadIdx.x;
    if (blk < 64) {
        __shared__ float WfL[4096];   // 4 q rows
        __shared__ float D1L[4096];   // 4 oc slices [ci*16+tap]
        int j = blk >> 3, q4 = blk & 7;
        for (int e = t; e < 4096; e += 256) {
            int qq = e >> 10, k = e & 1023;
            WfL[e] = Wf[(size_t)(q4 * 4 + qq) * 1024 + k];
        }
        for (int e = t; e < 4096; e += 256) {
            int ocg = e >> 10, r = e & 1023;
            D1L[e] = D1[(size_t)(ocg * 8 + j) * 1024 + r];
        }
        __syncthreads();
        int p = t & 63, ocg = t >> 6;
        int y = p >> 3, x = p & 7;
        float acc[4] = {0.f, 0.f, 0.f, 0.f};
        #pragma unroll
        for (int sy = 0; sy < 2; sy++) {
            int ky = (y & 1) + 2 * sy;
            int iy = ((y + ky) >> 1) - 1;
            if ((unsigned)iy >= 4u) continue;
            #pragma unroll
            for (int sx = 0; sx < 2; sx++) {
                int kx = (x & 1) + 2 * sx;
                int ix = ((x + kx) >> 1) - 1;
                if ((unsigned)ix >= 4u) continue;
                const float* dl = D1L + ocg * 1024 + ky * 4 + kx;
                const float* wl = WfL + iy * 4 + ix;
                for (int ci = 0; ci < 64; ci++) {
                    float wv = dl[ci * 16];
                    int kb = ci * 16;
                    acc[0] = fmaf(wl[kb],        wv, acc[0]);
                    acc[1] = fmaf(wl[1024 + kb], wv, acc[1]);
                    acc[2] = fmaf(wl[2048 + kb], wv, acc[2]);
                    acc[3] = fmaf(wl[3072 + kb], wv, acc[3]);
                }
            }
        }
        float4 o4 = make_float4(acc[0], acc[1], acc[2], acc[3]);
        ((float4*)(ws + WS_M1))[blk * 256 + t] = o4;
    } else {
        // c1: blocks 64..79, 2 oc per block, 2 threads per output (ci halves)
        __shared__ float bfL[1024];
        __shared__ float D1c[2048];
        int bb = blk - 64;
        for (int e = t; e < 1024; e += 256) bfL[e] = bf[e];
        for (int e = t; e < 2048; e += 256) D1c[e] = D1[(size_t)bb * 2048 + e];
        __syncthreads();
        int oidx = t >> 1, half = t & 1;
        int ocr = oidx >> 6, p = oidx & 63;
        int y = p >> 3, x = p & 7;
        float acc = 0.f;
        #pragma unroll
        for (int sy = 0; sy < 2; sy++) {
            int ky = (y & 1) + 2 * sy;
            int iy = ((y + ky) >> 1) - 1;
            if ((unsigned)iy >= 4u) continue;
            #pragma unroll
            for (int sx = 0; sx < 2; sx++) {
                int kx = (x & 1) + 2 * sx;
                int ix = ((x + kx) >> 1) - 1;
                if ((unsigned)ix >= 4u) continue;
                const float* dl = D1c + ocr * 1024 + half * 512 + ky * 4 + kx;
                const float* wl = bfL + half * 512 + iy * 4 + ix;
                for (int cc = 0; cc < 32; cc++)
                    acc = fmaf(wl[cc * 16], dl[cc * 16], acc);
            }
        }
        acc += __shfl_down(acc, 1, 64);
        if (half == 0) {
            int oc = bb * 2 + ocr;
            ws[WS_C1 + (oc & 7) * 256 + (oc >> 3) * 64 + p] = acc + d1[oc];
        }
    }
}

// ---------------- reparameterize + decoder weight transpose (fused) ----------------
__global__ __launch_bounds__(256) void reparam_prep(
    const float* __restrict__ s0mu, const float* __restrict__ s0lv,
    const float* __restrict__ v0mu, const float* __restrict__ v0lv,
    const float* __restrict__ eps_s, const float* __restrict__ eps_v,
    const float* __restrict__ D2, const float* __restrict__ D3,
    float* __restrict__ ws,
    float* __restrict__ qm, float* __restrict__ qlv,
    float* __restrict__ ztL, float* __restrict__ logp)
{
    int n = blockIdx.x, t = threadIdx.x;
    int idx = n * 256 + t;
    if (idx < 8192)      dec_tr(D2, ws + WS_WT2, idx,        32, 16);
    else if (idx < 8448) dec_tr(D3, ws + WS_WT3, idx - 8192, 16, 1);
    if (t < 64) {
        int q = t & 31;
        float mu, lvv, ep;
        if (t < 32) { mu = v0mu[n*32+q]; lvv = v0lv[n*32+q]; ep = eps_v[n*32+q]; }
        else        { mu = s0mu[n*32+q]; lvv = s0lv[n*32+q]; ep = eps_s[n*32+q]; }
        float zv = fmaf(ep, expf(lvv), mu);
        qm[n*64 + t]  = mu;
        qlv[n*64 + t] = lvv;
        ztL[(size_t)n * T_S * 64 + t] = zv;
        float e2 = ep * ep;
        #pragma unroll
        for (int off = 32; off; off >>= 1) e2 += __shfl_down(e2, off, 64);
        if (t == 0) logp[n * T_S] = -0.5f * e2 - Q_S * LOG2PI_F;
    }
}

// ---------------- RK4 ODE (chain-split) ----------------
__global__ __launch_bounds__(256) void ode_kernel(
    const float* __restrict__ W1, const float* __restrict__ b1,
    const float* __restrict__ W2, const float* __restrict__ b2,
    float* __restrict__ ztL, float* __restrict__ logp)
{
    __shared__ float W2s[HDYN_S * Q_S];
    __shared__ float zeval[64];
    __shared__ float hsh[HDYN_S];
    __shared__ float dvred[HDYN_S];
    __shared__ float red4[4];
    int n = blockIdx.x;
    int t = threadIdx.x;

    for (int i = t; i < HDYN_S * Q_S; i += 256) W2s[i] = W2[i];
    float w1r[64];
    #pragma unroll
    for (int j = 0; j < 64; j++) w1r[j] = W1[j * HDYN_S + t];
    float b1r = b1[t];
    __syncthreads();
    float ck = 0.f;
    #pragma unroll
    for (int i = 0; i < Q_S; i++) ck = fmaf(w1r[i], W2s[t * Q_S + i], ck);

    size_t zoff = (size_t)n * T_S * 64;
    float zj = 0.f, ksumj = 0.f, zevalj = 0.f, lp = 0.f, lsum = 0.f;
    if (t < 64) { zj = ztL[zoff + t]; zevalj = zj; zeval[t] = zj; }
    if (t == 0) lp = logp[n * T_S];

    const float wc[4] = {1.f, 2.f, 2.f, 1.f};
    const float ac[3] = {0.5f * DT_S, 0.5f * DT_S, DT_S};

    for (int step = 1; step < T_S; step++) {
        for (int e = 0; e < 4; e++) {
            __syncthreads();
            float p0 = 0.f, p1 = 0.f, p2 = 0.f, p3 = 0.f;
            #pragma unroll
            for (int j = 0; j < 16; j++) {
                p0 = fmaf(zeval[j],      w1r[j],      p0);
                p1 = fmaf(zeval[j + 16], w1r[j + 16], p1);
                p2 = fmaf(zeval[j + 32], w1r[j + 32], p2);
                p3 = fmaf(zeval[j + 48], w1r[j + 48], p3);
            }
            float pre = b1r + ((p0 + p1) + (p2 + p3));
            float hk = tanhf(pre);
            hsh[t] = hk;
            float gk = (1.f - hk * hk) * ck;
            #pragma unroll
            for (int off = 32; off; off >>= 1) gk += __shfl_down(gk, off, 64);
            if ((t & 63) == 0) red4[t >> 6] = gk;
            __syncthreads();
            {
                int i = t & 31, p = t >> 5;
                float a0 = 0.f, a1 = 0.f;
                #pragma unroll
                for (int kk = 0; kk < 16; kk++) {
                    a0 = fmaf(hsh[p * 32 + kk],      W2s[(p * 32 + kk) * Q_S + i],      a0);
                    a1 = fmaf(hsh[p * 32 + 16 + kk], W2s[(p * 32 + 16 + kk) * Q_S + i], a1);
                }
                dvred[t] = a0 + a1;
            }
            __syncthreads();
            if (t < 64) {
                float tr = red4[0] + red4[1] + red4[2] + red4[3];
                float zv_shfl = __shfl(zevalj, (t >= 32) ? (t - 32) : t, 64);
                float kzv;
                if (t < 32) {
                    float dvi = b2[t];
                    #pragma unroll
                    for (int p = 0; p < 8; p++) dvi += dvred[p * 32 + t];
                    kzv = dvi;
                } else kzv = zv_shfl;
                if (e == 0) ksumj = kzv; else ksumj = fmaf(wc[e], kzv, ksumj);
                if (t == 0) { float kl = -tr; lsum = (e == 0) ? kl : fmaf(wc[e], kl, lsum); }
                if (e < 3) {
                    zevalj = fmaf(ac[e], kzv, zj);
                    zeval[t] = zevalj;
                } else {
                    zj = fmaf(DT_S / 6.f, ksumj, zj);
                    zevalj = zj; zeval[t] = zj;
                    ztL[zoff + step * 64 + t] = zj;
                    if (t == 0) { lp = fmaf(DT_S / 6.f, lsum, lp); logp[n * T_S + step] = lp; }
                }
            }
        }
    }
}

// ---------------- fused decoder v7: composed M1 GEMV replaces fc3+deconv1 ----------
// Region B (regB, 4160 f): h2f full [16][16] pos, ci stride 16, row stride 260
// Region A (regA, 3600 f): h1f zero-padded [y+1:0..9]*360 + [x+1:0..9]*36 + oc(0..31)
//                          (360%32=8, 36%32=4 -> deconv2 reads bank-uniform)
//                          xst 32x36 aliased after h1f dead
__global__ __launch_bounds__(256) void decoder5(
    const float* __restrict__ ztL, const float* __restrict__ M1L, const float* __restrict__ c1L,
    const float* __restrict__ wt2, const float* __restrict__ d2,
    const float* __restrict__ wt3, const float* __restrict__ d3,
    const float* __restrict__ X, float* __restrict__ Xrec, float* __restrict__ lhood)
{
    __shared__ float zs[32];
    __shared__ float regA[3600];
    __shared__ float regB[4160];
    __shared__ float sh4[4];
    float* h2f = regB;
    float* h1f = regA;
    float* xst = regA;
    const int bidx = blockIdx.x;
    const int t = threadIdx.x;
    const int wu = __builtin_amdgcn_readfirstlane(t >> 6);   // wave id, provably uniform
    const int l = t & 63;
    const int py = wu >> 1, px = wu & 1;

    // ---- P0: zero h1f pad region + load z ----
    if (t < 32) zs[t] = ztL[(size_t)bidx * 64 + 32 + t];
    {
        float4 z4 = make_float4(0.f, 0.f, 0.f, 0.f);
        for (int e = t; e < 900; e += 256) ((float4*)regA)[e] = z4;   // h1f 3600 f
    }
    __syncthreads();

    // ---- P1: h1 = relu(M1 @ z_s + c1)  (composed fc3+deconv1) ----
    {
        float acc[8];
        #pragma unroll
        for (int j = 0; j < 8; j++) acc[j] = c1L[j * 256 + t];
        const float4* M14 = (const float4*)M1L;
        #pragma unroll
        for (int q4 = 0; q4 < 8; q4++) {
            float4 z4 = *(const float4*)(zs + q4 * 4);
            #pragma unroll
            for (int j = 0; j < 8; j++) {
                float4 m = M14[(j * 8 + q4) * 256 + t];
                acc[j] = fmaf(z4.x, m.x, fmaf(z4.y, m.y, fmaf(z4.z, m.z, fmaf(z4.w, m.w, acc[j]))));
            }
        }
        int p = t & 63, ocg = t >> 6;
        int y = p >> 3, x = p & 7;
        float* hp = h1f + (y + 1) * 360 + (x + 1) * 36 + ocg * 8;
        float4 r0, r1;
        r0.x = fmaxf(acc[0], 0.f); r0.y = fmaxf(acc[1], 0.f);
        r0.z = fmaxf(acc[2], 0.f); r0.w = fmaxf(acc[3], 0.f);
        r1.x = fmaxf(acc[4], 0.f); r1.y = fmaxf(acc[5], 0.f);
        r1.z = fmaxf(acc[6], 0.f); r1.w = fmaxf(acc[7], 0.f);
        *(float4*)(hp)     = r0;
        *(float4*)(hp + 4) = r1;
    }
    __syncthreads();

    // ---- deconv2: thread = 1 pos x ALL 16 oc; weights fully wave-uniform (s_load) ----
    {
        int a = l >> 3, b = l & 7;     // output pos2 in plane (py,px)
        float acc[16];
        #pragma unroll
        for (int j = 0; j < 16; j++) acc[j] = d2[j];
        #pragma unroll
        for (int sy = 0; sy < 2; sy++) {
            int ky = py + 2 * sy;
            int iyf = a + py + sy - 1;          // -1..8, pad covers
            #pragma unroll
            for (int sx = 0; sx < 2; sx++) {
                int kx = px + 2 * sx;
                int ixf = b + px + sx - 1;
                const float4* ip4 = (const float4*)(h1f + (iyf + 1) * 360 + (ixf + 1) * 36);
                const float* wb = wt2 + (ky * 4 + kx) * 512;   // uniform
                #pragma unroll 2
                for (int cc = 0; cc < 8; cc++) {
                    float4 v = ip4[cc];
                    float vv[4] = {v.x, v.y, v.z, v.w};
                    #pragma unroll
                    for (int r = 0; r < 4; r++) {
                        const float4* wq = (const float4*)(wb + (cc * 4 + r) * 16);
                        float4 w0 = wq[0], w1 = wq[1], w2 = wq[2], w3 = wq[3];
                        float vr = vv[r];
                        acc[0]  = fmaf(vr, w0.x, acc[0]);
                        acc[1]  = fmaf(vr, w0.y, acc[1]);
                        acc[2]  = fmaf(vr, w0.z, acc[2]);
                        acc[3]  = fmaf(vr, w0.w, acc[3]);
                        acc[4]  = fmaf(vr, w1.x, acc[4]);
                        acc[5]  = fmaf(vr, w1.y, acc[5]);
                        acc[6]  = fmaf(vr, w1.z, acc[6]);
                        acc[7]  = fmaf(vr, w1.w, acc[7]);
                        acc[8]  = fmaf(vr, w2.x, acc[8]);
                        acc[9]  = fmaf(vr, w2.y, acc[9]);
                        acc[10] = fmaf(vr, w2.z, acc[10]);
                        acc[11] = fmaf(vr, w2.w, acc[11]);
                        acc[12] = fmaf(vr, w3.x, acc[12]);
                        acc[13] = fmaf(vr, w3.y, acc[13]);
                        acc[14] = fmaf(vr, w3.z, acc[14]);
                        acc[15] = fmaf(vr, w3.w, acc[15]);
                    }
                }
            }
        }
        // h2f is regB (no alias with h1f) -> no extra barrier needed before write
        float* hq = h2f + (2 * a + py) * 260 + (2 * b + px) * 16;
        #pragma unroll
        for (int j = 0; j < 4; j++) {
            float4 r;
            r.x = fmaxf(acc[j*4+0], 0.f);
            r.y = fmaxf(acc[j*4+1], 0.f);
            r.z = fmaxf(acc[j*4+2], 0.f);
            r.w = fmaxf(acc[j*4+3], 0.f);
            *(float4*)(hq + j * 4) = r;
        }
    }
    __syncthreads();

    // ---- deconv3: full [16,16,16] -> [32,32]; weights via uniform s_load ----
    // (writes xst aliasing h1f: safe, all h1f reads completed at the barrier above)
    {
        int oy2 = l >> 2, b3 = l & 3;
        float acc[4];
        float d30 = d3[0];
        #pragma unroll
        for (int k = 0; k < 4; k++) acc[k] = d30;
        #pragma unroll
        for (int sy = 0; sy < 2; sy++) {
            int ky = py + 2 * sy;
            int iy = oy2 + py + sy - 1;
            if ((unsigned)iy >= 16u) continue;
            #pragma unroll
            for (int sx = 0; sx < 2; sx++) {
                int kx = px + 2 * sx;
                int cx = px + sx - 1;
                const float* wvp = wt3 + (ky * 4 + kx) * 16;   // uniform
                #pragma unroll
                for (int k = 0; k < 4; k++) {
                    int ix = b3 + 4 * k + cx;
                    if ((unsigned)ix >= 16u) continue;
                    const float4* in4 = (const float4*)(h2f + iy * 260 + ix * 16);
                    #pragma unroll
                    for (int cc = 0; cc < 4; cc++) {
                        float4 v = in4[cc];
                        float4 wq = ((const float4*)wvp)[cc];
                        acc[k] = fmaf(v.x, wq.x, acc[k]);
                        acc[k] = fmaf(v.y, wq.y, acc[k]);
                        acc[k] = fmaf(v.z, wq.z, acc[k]);
                        acc[k] = fmaf(v.w, wq.w, acc[k]);
                    }
                }
            }
        }
        int oy = 2 * oy2 + py;
        #pragma unroll
        for (int k = 0; k < 4; k++) {
            int ox = 2 * (b3 + 4 * k) + px;
            xst[oy * 36 + ox] = 1.f / (1.f + expf(-acc[k]));
        }
    }
    __syncthreads();

    // ---- coalesced Xrec write + X read + lhood ----
    {
        int row = t >> 3, col = (t & 7) * 4;
        float4 xr4 = *(const float4*)(xst + row * 36 + col);
        *(float4*)(Xrec + (size_t)bidx * 1024 + t * 4) = xr4;
        float4 xi4 = *(const float4*)(X + (size_t)bidx * 1024 + t * 4);
        float ll = 0.f;
        ll += logf(0.001f + xr4.x) * xi4.x + logf(1.001f - xr4.x) * (1.f - xi4.x);
        ll += logf(0.001f + xr4.y) * xi4.y + logf(1.001f - xr4.y) * (1.f - xi4.y);
        ll += logf(0.001f + xr4.z) * xi4.z + logf(1.001f - xr4.z) * (1.f - xi4.z);
        ll += logf(0.001f + xr4.w) * xi4.w + logf(1.001f - xr4.w) * (1.f - xi4.w);
        #pragma unroll
        for (int off = 32; off; off >>= 1) ll += __shfl_down(ll, off, 64);
        if ((t & 63) == 0) sh4[t >> 6] = ll;
    }
    __syncthreads();
    if (t == 0) atomicAdd(&lhood[bidx / T_S], sh4[0] + sh4[1] + sh4[2] + sh4[3]);
}

// ---------------- kl_z ----------------
__global__ __launch_bounds__(64) void klz_kernel(
    const float* __restrict__ ztL, const float* __restrict__ logp, float* __restrict__ klz)
{
    int n = blockIdx.x, t = threadIdx.x;
    float v = 0.f;
    if (t < T_S) {
        const float* z = ztL + ((size_t)n * T_S + t) * 64;
        float s2 = 0.f;
        #pragma unroll
        for (int j = 0; j < 64; j++) s2 = fmaf(z[j], z[j], s2);
        v = logp[n * T_S + t] - (-0.5f * s2 - Q_S * LOG2PI_F);
    }
    #pragma unroll
    for (int off = 32; off; off >>= 1) v += __shfl_down(v, off, 64);
    if (t == 0) klz[n] = v;
}

// ---------------- final scalars (+ kl_w fused) ----------------
__global__ __launch_bounds__(256) void final2(
    const float* __restrict__ lhood, const float* __restrict__ klz,
    const float* __restrict__ W1, const float* __restrict__ W2,
    const int* __restrict__ Ndata, float* __restrict__ outs)
{
    __shared__ float shA[4], shB[4], shC[4];
    int t = threadIdx.x;
    float a = lhood[t];
    float b = klz[t];
    float c = 0.f;
    for (int i = t; i < 64 * HDYN_S; i += 256) c = fmaf(W1[i], W1[i], c);
    for (int i = t; i < HDYN_S * Q_S; i += 256) c = fmaf(W2[i], W2[i], c);
    #pragma unroll
    for (int off = 32; off; off >>= 1) {
        a += __shfl_down(a, off, 64);
        b += __shfl_down(b, off, 64);
        c += __shfl_down(c, off, 64);
    }
    if ((t & 63) == 0) { shA[t >> 6] = a; shB[t >> 6] = b; shC[t >> 6] = c; }
    __syncthreads();
    if (t == 0) {
        float Nd = (float)Ndata[0];
        float lh = Nd * ((shA[0] + shA[1] + shA[2] + shA[3]) / 256.f);
        float kz = Nd * ((shB[0] + shB[1] + shB[2] + shB[3]) / 256.f);
        float bkw = 0.5f * (shC[0] + shC[1] + shC[2] + shC[3]);
        outs[0] = lh - kz - bkw;
        outs[1] = lh;
        outs[2] = kz;
        outs[3] = bkw;
    }
}

extern "C" void kernel_launch(void* const* d_in, const int* in_sizes, int n_in,
                              void* d_out, int out_size, void* d_ws, size_t ws_size,
                              hipStream_t stream) {
    const float* X      = (const float*)d_in[0];
    const float* eps_s0 = (const float*)d_in[1];
    const float* eps_v0 = (const float*)d_in[2];
    const float* Cs1 = (const float*)d_in[3],  *cs1 = (const float*)d_in[4];
    const float* Cs2 = (const float*)d_in[5],  *cs2 = (const float*)d_in[6];
    const float* Cs3 = (const float*)d_in[7],  *cs3 = (const float*)d_in[8];
    const float* Wsm = (const float*)d_in[9],  *bsm = (const float*)d_in[10];
    const float* Wsl = (const float*)d_in[11], *bsl = (const float*)d_in[12];
    const float* Cv1 = (const float*)d_in[13], *cv1 = (const float*)d_in[14];
    const float* Cv2 = (const float*)d_in[15], *cv2 = (const float*)d_in[16];
    const float* Cv3 = (const float*)d_in[17], *cv3 = (const float*)d_in[18];
    const float* Wvm = (const float*)d_in[19], *bvm = (const float*)d_in[20];
    const float* Wvl = (const float*)d_in[21], *bvl = (const float*)d_in[22];
    const float* W1  = (const float*)d_in[23], *b1  = (const float*)d_in[24];
    const float* W2  = (const float*)d_in[25], *b2  = (const float*)d_in[26];
    const float* Wf  = (const float*)d_in[27], *bf  = (const float*)d_in[28];
    const float* D1  = (const float*)d_in[29], *d1  = (const float*)d_in[30];
    const float* D2  = (const float*)d_in[31], *d2  = (const float*)d_in[32];
    const float* D3  = (const float*)d_in[33], *d3  = (const float*)d_in[34];
    const int*   Ndata = (const int*)d_in[35];

    float* out = (float*)d_out;
    float* ws  = (float*)d_ws;

    prep_enc<<<331, 256, 0, stream>>>(Cs1, Cv1, Cs2, Cv2, Cs3, Cv3, ws);

    // ---- encoder s (frame 0) ----
    conv1_lds<1><<<dim3(256, 2), 256, 0, stream>>>(X, ws + TC_S1, cs1, ws + WS_A1);
    conv2_lds<<<dim3(256, 2), 256, 0, stream>>>(ws + WS_A1, ws + TC_S2, cs2, ws + WS_A2);
    conv3_lds<<<dim3(256, 2), 256, 0, stream>>>(ws + WS_A2, ws + TC_S3, cs3, ws + WS_A3);
    fc_enc2<<<256, 256, 0, stream>>>(ws + WS_A3, Wsm, bsm, Wsl, bsl, ws + WS_S0MU, ws + WS_S0LV);

    // ---- encoder v (10 frames as channels) ----
    conv1_lds<10><<<dim3(256, 2), 256, 0, stream>>>(X, ws + TC_V1, cv1, ws + WS_A1);
    conv2_lds<<<dim3(256, 2), 256, 0, stream>>>(ws + WS_A1, ws + TC_V2, cv2, ws + WS_A2);
    conv3_lds<<<dim3(256, 2), 256, 0, stream>>>(ws + WS_A2, ws + TC_V3, cv3, ws + WS_A3);
    fc_enc2<<<256, 256, 0, stream>>>(ws + WS_A3, Wvm, bvm, Wvl, bvl, ws + WS_V0MU, ws + WS_V0LV);

    // ---- compose fc3+deconv1 (A2 region now dead) ----
    m1_prep<<<80, 256, 0, stream>>>(Wf, bf, D1, d1, ws);

    // ---- reparameterize + decoder weight transpose ----
    reparam_prep<<<256, 256, 0, stream>>>(ws + WS_S0MU, ws + WS_S0LV, ws + WS_V0MU, ws + WS_V0LV,
                                          eps_s0, eps_v0, D2, D3, ws,
                                          out + OUT_QM, out + OUT_QLV,
                                          out + OUT_ZT, ws + WS_LOGP);

    // ---- RK4 ODE ----
    ode_kernel<<<256, 256, 0, stream>>>(W1, b1, W2, b2, out + OUT_ZT, ws + WS_LOGP);

    // ---- fused decoder ----
    decoder5<<<5120, 256, 0, stream>>>(out + OUT_ZT, ws + WS_M1, ws + WS_C1,
                                       ws + WS_WT2, d2, ws + WS_WT3, d3,
                                       X, out + OUT_XREC, ws + WS_LHOOD);

    // ---- ELBO pieces ----
    klz_kernel<<<256, 64, 0, stream>>>(out + OUT_ZT, ws + WS_LOGP, ws + WS_KLZ);
    final2<<<1, 256, 0, stream>>>(ws + WS_LHOOD, ws + WS_KLZ, W1, W2, Ndata,
                                  out + OUT_SCAL);
}

// Round 3
// 495.328 us; speedup vs baseline: 1.2305x; 1.0142x over previous
//
#include <hip/hip_runtime.h>
#include <math.h>

#define N_S 256
#define T_S 20
#define D_S 32
#define NF_S 16
#define Q_S 32
#define HDYN_S 256
#define HDIM_S 1024
#define VSTEPS_S 10
#define DT_S 0.1f
#define LOG2PI_F 1.8378770664093453f

// ---- d_out offsets (floats) ----
#define OUT_XREC 0
#define OUT_QM   5242880
#define OUT_QLV  5259264
#define OUT_ZT   5275648
#define OUT_SCAL 5603328

// ---- d_out scratch (inside XREC region, dead until decoder5) ----
#define OS_A1S   0          // 1048576
#define OS_A2S   1048576    // 524288
#define OS_A3S   1572864    // 262144  (ends 1835008 < 5242880)

// ---- workspace offsets (floats) ----
#define WS_A1V   0          // 1048576 (v conv1 out)
#define WS_A3V   0          // 262144  (alias: A1V dead after conv2)
#define WS_WT2   32768      // 8192  (written by reparam over dead A3V)
#define WS_WT3   40960      // 256
#define WS_A2V   1048576    // 524288 (v conv2 out)
#define WS_M1    1048576    // 65536 (written by reparam over dead A2V)
#define WS_C1    1114112    // 2048
#define WS_S0MU  1572864
#define WS_S0LV  1581056
#define WS_V0MU  1589248
#define WS_V0LV  1597440
#define WS_LOGP  1605632
#define WS_LHOOD 1610752
#define WS_KLZ   1611008
#define WS_KLW   1611264
#define WS_TC    1611520
#define TC_S1 (WS_TC + 0)
#define TC_V1 (WS_TC + 256)
#define TC_S2 (WS_TC + 2816)
#define TC_V2 (WS_TC + 11008)
#define TC_S3 (WS_TC + 19200)
#define TC_V3 (WS_TC + 51968)

// ---------------- weight transposes ----------------
__device__ inline void enc_tr(const float* __restrict__ src, float* __restrict__ dst,
                              int e, int CI, int CO) {
    int co = e % CO; int r = e / CO; int tap = r & 15; int ci = r >> 4;
    dst[e] = src[(co * CI + ci) * 16 + tap];
}
__device__ inline void dec_tr(const float* __restrict__ src, float* __restrict__ dst,
                              int e, int CI, int CO) {
    int co = e % CO; int r = e / CO; int ci = r % CI; int tap = r / CI;
    dst[e] = src[(co * CI + ci) * 16 + tap];
}

__global__ __launch_bounds__(256) void prep_enc(
    const float* __restrict__ Cs1, const float* __restrict__ Cv1,
    const float* __restrict__ Cs2, const float* __restrict__ Cv2,
    const float* __restrict__ Cs3, const float* __restrict__ Cv3,
    float* __restrict__ ws)
{
    int idx = blockIdx.x * 256 + threadIdx.x;
    if (blockIdx.x == 0) ws[WS_LHOOD + threadIdx.x] = 0.f;   // fold in lhood zeroing
    if (idx < 256)        enc_tr(Cs1, ws + TC_S1, idx,          1, 16);
    else if (idx < 2816)  enc_tr(Cv1, ws + TC_V1, idx - 256,   10, 16);
    else if (idx < 11008) enc_tr(Cs2, ws + TC_S2, idx - 2816,  16, 32);
    else if (idx < 19200) enc_tr(Cv2, ws + TC_V2, idx - 11008, 16, 32);
    else if (idx < 51968) enc_tr(Cs3, ws + TC_S3, idx - 19200, 32, 64);
    else if (idx < 84736) enc_tr(Cv3, ws + TC_V3, idx - 51968, 32, 64);
}

// ---------------- conv1 both encoders: z=0 -> s (cin=1), z=1 -> v (cin=10) ------------
// weights/bias via wave-uniform scalar loads (no LDS staging)
__global__ __launch_bounds__(256) void conv1_both(
    const float* __restrict__ x,
    const float* __restrict__ wts, const float* __restrict__ bs, float* __restrict__ outs,
    const float* __restrict__ wtv, const float* __restrict__ bv, float* __restrict__ outv)
{
    __shared__ float xin[10 * 630];   // ci*630 + r*35 + (gx+1), r = local row 0..17
    int sel = blockIdx.z;
    int cin = sel ? 10 : 1;
    const float* wt = sel ? wtv : wts;
    const float* bias = sel ? bv : bs;
    float* out = sel ? outv : outs;

    int b = blockIdx.x, yh = blockIdx.y, t = threadIdx.x;
    for (int e = t; e < cin * 576; e += 256) {
        int ci = e / 576;
        int r = (e >> 5) - ci * 18;
        int cx = e & 31;
        int gy = yh * 16 - 1 + r;
        float v = (gy >= 0 && gy < 32) ? x[(size_t)b * 20480 + ci * 1024 + gy * 32 + cx] : 0.f;
        xin[ci * 630 + r * 35 + cx + 1] = v;
    }
    for (int e = t; e < cin * 18; e += 256) {
        int ci = e / 18, r = e - ci * 18;
        xin[ci * 630 + r * 35 + 0] = 0.f;
        xin[ci * 630 + r * 35 + 33] = 0.f;
    }
    __syncthreads();

    int ocq = __builtin_amdgcn_readfirstlane(t >> 7);   // wave-uniform
    int p = t & 127;
    int oyl = p >> 4, ox = p & 15;
    const float* wg = wt + ocq * 8;
    float acc[8];
    #pragma unroll
    for (int j = 0; j < 8; j++) acc[j] = bias[ocq * 8 + j];
    for (int ci = 0; ci < cin; ci++) {
        const float* xc = xin + ci * 630;
        const float* wc = wg + ci * 256;
        #pragma unroll
        for (int ky = 0; ky < 4; ky++) {
            const float* xr = xc + (2 * oyl + ky) * 35;
            #pragma unroll
            for (int kx = 0; kx < 4; kx++) {
                float v = xr[2 * ox + kx];
                const float4* w4 = (const float4*)(wc + (ky * 4 + kx) * 16);
                float4 wa = w4[0], wb2 = w4[1];
                acc[0] = fmaf(v, wa.x, acc[0]);
                acc[1] = fmaf(v, wa.y, acc[1]);
                acc[2] = fmaf(v, wa.z, acc[2]);
                acc[3] = fmaf(v, wa.w, acc[3]);
                acc[4] = fmaf(v, wb2.x, acc[4]);
                acc[5] = fmaf(v, wb2.y, acc[5]);
                acc[6] = fmaf(v, wb2.z, acc[6]);
                acc[7] = fmaf(v, wb2.w, acc[7]);
            }
        }
    }
    int oy = yh * 8 + oyl;
    size_t ob = (size_t)b * 4096 + (size_t)(ocq * 8) * 256 + oy * 16 + ox;
    #pragma unroll
    for (int j = 0; j < 8; j++) out[ob + (size_t)j * 256] = fmaxf(acc[j], 0.f);
}

// ---------------- conv2 both: z selects encoder; y = oc-half; scalar weights ----------
__global__ __launch_bounds__(256) void conv2_both(
    const float* __restrict__ a1s, const float* __restrict__ wts, const float* __restrict__ bsb,
    float* __restrict__ outs,
    const float* __restrict__ a1v, const float* __restrict__ wtv, const float* __restrict__ bvb,
    float* __restrict__ outv)
{
    __shared__ float xin[16 * 272];
    int sel = blockIdx.z;
    const float* a1 = sel ? a1v : a1s;
    const float* wt = sel ? wtv : wts;   // [ci][tap][32oc]
    const float* bias = sel ? bvb : bsb;
    float* out = sel ? outv : outs;

    int b = blockIdx.x, h = blockIdx.y, t = threadIdx.x;
    for (int e = t; e < 4096; e += 256) {
        int ci = e >> 8, r = e & 255, iy = r >> 4, ix = r & 15;
        xin[ci * 272 + iy * 17 + ix] = a1[(size_t)b * 4096 + e];
    }
    __syncthreads();

    int ocq = __builtin_amdgcn_readfirstlane(t >> 6);   // wave-uniform
    int p = t & 63;
    int pa = p >> 3, pb = p & 7;       // oy, ox
    int hbase = h * 16 + ocq * 4;
    float acc[4];
    #pragma unroll
    for (int j = 0; j < 4; j++) acc[j] = bias[hbase + j];
    for (int ci = 0; ci < 16; ci++) {
        const float* xc = xin + ci * 272;
        const float* wc = wt + ci * 512 + hbase;
        #pragma unroll
        for (int ky = 0; ky < 4; ky++) {
            int iy = 2 * pa - 1 + ky;
            if ((unsigned)iy >= 16u) continue;
            const float* xr = xc + iy * 17;
            #pragma unroll
            for (int kx = 0; kx < 4; kx++) {
                int ix = 2 * pb - 1 + kx;
                if ((unsigned)ix >= 16u) continue;
                float v = xr[ix];
                float4 wv = *(const float4*)(wc + (ky * 4 + kx) * 32);
                acc[0] = fmaf(v, wv.x, acc[0]);
                acc[1] = fmaf(v, wv.y, acc[1]);
                acc[2] = fmaf(v, wv.z, acc[2]);
                acc[3] = fmaf(v, wv.w, acc[3]);
            }
        }
    }
    size_t ob = (size_t)b * 2048 + (size_t)(hbase) * 64 + pa * 8 + pb;
    #pragma unroll
    for (int j = 0; j < 4; j++) out[ob + (size_t)j * 64] = fmaxf(acc[j], 0.f);
}

// ---------------- conv3 both (weights lane-varying -> keep LDS) ----------------
__global__ __launch_bounds__(256) void conv3_both(
    const float* __restrict__ a2s, const float* __restrict__ wts, const float* __restrict__ bsb,
    float* __restrict__ outs,
    const float* __restrict__ a2v, const float* __restrict__ wtv, const float* __restrict__ bvb,
    float* __restrict__ outv)
{
    __shared__ float xin[32 * 72];
    __shared__ float wl[16384];
    __shared__ float bl[32];
    int sel = blockIdx.z;
    const float* a2 = sel ? a2v : a2s;
    const float* wt = sel ? wtv : wts;
    const float* bias = sel ? bvb : bsb;
    float* out = sel ? outv : outs;

    int b = blockIdx.x, h = blockIdx.y, t = threadIdx.x;
    for (int e = t; e < 2048; e += 256) {
        int ci = e >> 6, r = e & 63, iy = r >> 3, ix = r & 7;
        xin[ci * 72 + iy * 9 + ix] = a2[(size_t)b * 2048 + e];
    }
    for (int e4 = t; e4 < 4096; e4 += 256) {
        int grp = e4 >> 3, c4 = e4 & 7;
        ((float4*)wl)[e4] = ((const float4*)(wt + grp * 64 + h * 32))[c4];
    }
    if (t < 32) bl[t] = bias[h * 32 + t];
    __syncthreads();

    int ocq = t >> 4, p = t & 15;
    int pa = p >> 2, pb = p & 3;
    float a0 = bl[ocq * 2], a1 = bl[ocq * 2 + 1];
    for (int ci = 0; ci < 32; ci++) {
        const float* xc = xin + ci * 72;
        const float* wc = wl + ci * 512 + ocq * 2;
        #pragma unroll
        for (int ky = 0; ky < 4; ky++) {
            int iy = 2 * pa - 1 + ky;
            if ((unsigned)iy >= 8u) continue;
            const float* xr = xc + iy * 9;
            #pragma unroll
            for (int kx = 0; kx < 4; kx++) {
                int ix = 2 * pb - 1 + kx;
                if ((unsigned)ix >= 8u) continue;
                float v = xr[ix];
                float2 wv = *(const float2*)(wc + (ky * 4 + kx) * 32);
                a0 = fmaf(v, wv.x, a0);
                a1 = fmaf(v, wv.y, a1);
            }
        }
    }
    size_t ob = (size_t)b * 1024 + (size_t)(h * 32 + ocq * 2) * 16 + pa * 4 + pb;
    out[ob] = fmaxf(a0, 0.f);
    out[ob + 16] = fmaxf(a1, 0.f);
}

// ---------------- encoder fc, both encoders (blockIdx.x >> 8 selects) ----------------
__global__ __launch_bounds__(256) void fc_both(
    const float* __restrict__ hs, const float* __restrict__ hv,
    const float* __restrict__ Wsm, const float* __restrict__ bsm,
    const float* __restrict__ Wsl, const float* __restrict__ bsl,
    const float* __restrict__ Wvm, const float* __restrict__ bvm,
    const float* __restrict__ Wvl, const float* __restrict__ bvl,
    float* __restrict__ mus, float* __restrict__ lvs,
    float* __restrict__ muv, float* __restrict__ lvv)
{
    __shared__ float pm[8][32], pl[8][32];
    int sel = blockIdx.x >> 8;
    int b = blockIdx.x & 255, t = threadIdx.x;
    const float* h  = sel ? hv : hs;
    const float* Wm = sel ? Wvm : Wsm;
    const float* bm = sel ? bvm : bsm;
    const float* Wl = sel ? Wvl : Wsl;
    const float* bl = sel ? bvl : bsl;
    float* mu = sel ? muv : mus;
    float* lv = sel ? lvv : lvs;

    int q = t & 31, c = t >> 5;
    const float* hb = h + (size_t)b * HDIM_S + c * 128;
    const float* wmp = Wm + (c * 128) * Q_S + q;
    const float* wlp = Wl + (c * 128) * Q_S + q;
    float am = 0.f, al = 0.f;
    #pragma unroll 4
    for (int k = 0; k < 128; k++) {
        float hv2 = hb[k];
        am = fmaf(hv2, wmp[k * Q_S], am);
        al = fmaf(hv2, wlp[k * Q_S], al);
    }
    pm[c][q] = am; pl[c][q] = al;
    __syncthreads();
    if (t < 32) {
        float s = bm[t];
        #pragma unroll
        for (int c2 = 0; c2 < 8; c2++) s += pm[c2][t];
        mu[b * Q_S + t] = s;
    } else if (t < 64) {
        int qq = t - 32;
        float s = bl[qq];
        #pragma unroll
        for (int c2 = 0; c2 < 8; c2++) s += pl[c2][qq];
        lv[b * Q_S + qq] = s;
    }
}

// ---------------- reparam + M1 compose + D2/D3 transposes (all folded) ----------------
// every block: reparam duty for n = blockIdx.x
// blocks 0..63:  M1 main GEMM blocks; 64..79: c1; 80..112: WT2/WT3 transposes
__global__ __launch_bounds__(256) void reparam_prep(
    const float* __restrict__ s0mu, const float* __restrict__ s0lv,
    const float* __restrict__ v0mu, const float* __restrict__ v0lv,
    const float* __restrict__ eps_s, const float* __restrict__ eps_v,
    const float* __restrict__ Wf, const float* __restrict__ bf,
    const float* __restrict__ D1, const float* __restrict__ d1,
    const float* __restrict__ D2, const float* __restrict__ D3,
    float* __restrict__ ws,
    float* __restrict__ qm, float* __restrict__ qlv,
    float* __restrict__ ztL, float* __restrict__ logp)
{
    __shared__ float shA[4096];
    __shared__ float shB[4096];
    int n = blockIdx.x, t = threadIdx.x;

    if (n < 64) {
        // M1[(y,x,oc)][q] = sum Wf[q][ci*16+iy*4+ix] * D1[oc*1024+ci*16+ky*4+kx]
        int j = n >> 3, q4 = n & 7;
        for (int e = t; e < 4096; e += 256) {
            int qq = e >> 10, k = e & 1023;
            shA[e] = Wf[(size_t)(q4 * 4 + qq) * 1024 + k];
        }
        for (int e = t; e < 4096; e += 256) {
            int ocg = e >> 10, r = e & 1023;
            shB[e] = D1[(size_t)(ocg * 8 + j) * 1024 + r];
        }
        __syncthreads();
        int p = t & 63, ocg = t >> 6;
        int y = p >> 3, x = p & 7;
        float acc[4] = {0.f, 0.f, 0.f, 0.f};
        #pragma unroll
        for (int sy = 0; sy < 2; sy++) {
            int ky = (y & 1) + 2 * sy;
            int iy = ((y + ky) >> 1) - 1;
            if ((unsigned)iy >= 4u) continue;
            #pragma unroll
            for (int sx = 0; sx < 2; sx++) {
                int kx = (x & 1) + 2 * sx;
                int ix = ((x + kx) >> 1) - 1;
                if ((unsigned)ix >= 4u) continue;
                const float* dl = shB + ocg * 1024 + ky * 4 + kx;
                const float* wl = shA + iy * 4 + ix;
                for (int ci = 0; ci < 64; ci++) {
                    float wv = dl[ci * 16];
                    int kb = ci * 16;
                    acc[0] = fmaf(wl[kb],        wv, acc[0]);
                    acc[1] = fmaf(wl[1024 + kb], wv, acc[1]);
                    acc[2] = fmaf(wl[2048 + kb], wv, acc[2]);
                    acc[3] = fmaf(wl[3072 + kb], wv, acc[3]);
                }
            }
        }
        ((float4*)(ws + WS_M1))[n * 256 + t] = make_float4(acc[0], acc[1], acc[2], acc[3]);
    } else if (n < 80) {
        // c1: 2 oc per block, 2 threads per output (ci halves)
        int bb = n - 64;
        for (int e = t; e < 1024; e += 256) shA[e] = bf[e];
        for (int e = t; e < 2048; e += 256) shB[e] = D1[(size_t)bb * 2048 + e];
        __syncthreads();
        int oidx = t >> 1, half = t & 1;
        int ocr = oidx >> 6, p = oidx & 63;
        int y = p >> 3, x = p & 7;
        float acc = 0.f;
        #pragma unroll
        for (int sy = 0; sy < 2; sy++) {
            int ky = (y & 1) + 2 * sy;
            int iy = ((y + ky) >> 1) - 1;
            if ((unsigned)iy >= 4u) continue;
            #pragma unroll
            for (int sx = 0; sx < 2; sx++) {
                int kx = (x & 1) + 2 * sx;
                int ix = ((x + kx) >> 1) - 1;
                if ((unsigned)ix >= 4u) continue;
                const float* dl = shB + ocr * 1024 + half * 512 + ky * 4 + kx;
                const float* wl = shA + half * 512 + iy * 4 + ix;
                for (int cc = 0; cc < 32; cc++)
                    acc = fmaf(wl[cc * 16], dl[cc * 16], acc);
            }
        }
        acc += __shfl_down(acc, 1, 64);
        if (half == 0) {
            int oc = bb * 2 + ocr;
            ws[WS_C1 + (oc & 7) * 256 + (oc >> 3) * 64 + p] = acc + d1[oc];
        }
    } else if (n < 113) {
        int idx = (n - 80) * 256 + t;
        if (idx < 8192)      dec_tr(D2, ws + WS_WT2, idx,        32, 16);
        else if (idx < 8448) dec_tr(D3, ws + WS_WT3, idx - 8192, 16, 1);
    }

    if (t < 64) {
        int q = t & 31;
        float mu, lvv2, ep;
        if (t < 32) { mu = v0mu[n*32+q]; lvv2 = v0lv[n*32+q]; ep = eps_v[n*32+q]; }
        else        { mu = s0mu[n*32+q]; lvv2 = s0lv[n*32+q]; ep = eps_s[n*32+q]; }
        float zv = fmaf(ep, expf(lvv2), mu);
        qm[n*64 + t]  = mu;
        qlv[n*64 + t] = lvv2;
        ztL[(size_t)n * T_S * 64 + t] = zv;
        float e2 = ep * ep;
        #pragma unroll
        for (int off = 32; off; off >>= 1) e2 += __shfl_down(e2, off, 64);
        if (t == 0) logp[n * T_S] = -0.5f * e2 - Q_S * LOG2PI_F;
    }
}

// ---------------- RK4 ODE (chain-split) + klz accumulation folded --------------------
__global__ __launch_bounds__(256) void ode_kernel(
    const float* __restrict__ W1, const float* __restrict__ b1,
    const float* __restrict__ W2, const float* __restrict__ b2,
    float* __restrict__ ztL, const float* __restrict__ logp,
    float* __restrict__ klz)
{
    __shared__ float W2s[HDYN_S * Q_S];
    __shared__ float zeval[64];
    __shared__ float hsh[HDYN_S];
    __shared__ float dvred[HDYN_S];
    __shared__ float red4[4];
    int n = blockIdx.x;
    int t = threadIdx.x;

    for (int i = t; i < HDYN_S * Q_S; i += 256) W2s[i] = W2[i];
    float w1r[64];
    #pragma unroll
    for (int j = 0; j < 64; j++) w1r[j] = W1[j * HDYN_S + t];
    float b1r = b1[t];
    __syncthreads();
    float ck = 0.f;
    #pragma unroll
    for (int i = 0; i < Q_S; i++) ck = fmaf(w1r[i], W2s[t * Q_S + i], ck);

    size_t zoff = (size_t)n * T_S * 64;
    float zj = 0.f, ksumj = 0.f, zevalj = 0.f, lp = 0.f, lsum = 0.f, klacc = 0.f;
    if (t < 64) { zj = ztL[zoff + t]; zevalj = zj; zeval[t] = zj; }
    if (t == 0) lp = logp[n * T_S];

    // klz contribution for step 0
    if (t < 64) {
        float e2 = zj * zj;
        #pragma unroll
        for (int off = 32; off; off >>= 1) e2 += __shfl_down(e2, off, 64);
        if (t == 0) klacc += lp - (-0.5f * e2 - Q_S * LOG2PI_F);
    }

    const float wc[4] = {1.f, 2.f, 2.f, 1.f};
    const float ac[3] = {0.5f * DT_S, 0.5f * DT_S, DT_S};

    for (int step = 1; step < T_S; step++) {
        for (int e = 0; e < 4; e++) {
            __syncthreads();
            float p0 = 0.f, p1 = 0.f, p2 = 0.f, p3 = 0.f;
            #pragma unroll
            for (int j = 0; j < 16; j++) {
                p0 = fmaf(zeval[j],      w1r[j],      p0);
                p1 = fmaf(zeval[j + 16], w1r[j + 16], p1);
                p2 = fmaf(zeval[j + 32], w1r[j + 32], p2);
                p3 = fmaf(zeval[j + 48], w1r[j + 48], p3);
            }
            float pre = b1r + ((p0 + p1) + (p2 + p3));
            float hk = tanhf(pre);
            hsh[t] = hk;
            float gk = (1.f - hk * hk) * ck;
            #pragma unroll
            for (int off = 32; off; off >>= 1) gk += __shfl_down(gk, off, 64);
            if ((t & 63) == 0) red4[t >> 6] = gk;
            __syncthreads();
            {
                int i = t & 31, p = t >> 5;
                float a0 = 0.f, a1 = 0.f;
                #pragma unroll
                for (int kk = 0; kk < 16; kk++) {
                    a0 = fmaf(hsh[p * 32 + kk],      W2s[(p * 32 + kk) * Q_S + i],      a0);
                    a1 = fmaf(hsh[p * 32 + 16 + kk], W2s[(p * 32 + 16 + kk) * Q_S + i], a1);
                }
                dvred[t] = a0 + a1;
            }
            __syncthreads();
            if (t < 64) {
                float tr = red4[0] + red4[1] + red4[2] + red4[3];
                float zv_shfl = __shfl(zevalj, (t >= 32) ? (t - 32) : t, 64);
                float kzv;
                if (t < 32) {
                    float dvi = b2[t];
                    #pragma unroll
                    for (int p = 0; p < 8; p++) dvi += dvred[p * 32 + t];
                    kzv = dvi;
                } else kzv = zv_shfl;
                if (e == 0) ksumj = kzv; else ksumj = fmaf(wc[e], kzv, ksumj);
                if (t == 0) { float kl = -tr; lsum = (e == 0) ? kl : fmaf(wc[e], kl, lsum); }
                if (e < 3) {
                    zevalj = fmaf(ac[e], kzv, zj);
                    zeval[t] = zevalj;
                } else {
                    zj = fmaf(DT_S / 6.f, ksumj, zj);
                    zevalj = zj; zeval[t] = zj;
                    ztL[zoff + step * 64 + t] = zj;
                    if (t == 0) lp = fmaf(DT_S / 6.f, lsum, lp);
                    // klz contribution for this step
                    float e2 = zj * zj;
                    #pragma unroll
                    for (int off = 32; off; off >>= 1) e2 += __shfl_down(e2, off, 64);
                    if (t == 0) klacc += lp - (-0.5f * e2 - Q_S * LOG2PI_F);
                }
            }
        }
    }
    if (t == 0) klz[n] = klacc;
}

// ---------------- fused decoder v7: composed M1 GEMV replaces fc3+deconv1 ----------
__global__ __launch_bounds__(256) void decoder5(
    const float* __restrict__ ztL, const float* __restrict__ M1L, const float* __restrict__ c1L,
    const float* __restrict__ wt2, const float* __restrict__ d2,
    const float* __restrict__ wt3, const float* __restrict__ d3,
    const float* __restrict__ X, float* __restrict__ Xrec, float* __restrict__ lhood)
{
    __shared__ float zs[32];
    __shared__ float regA[3600];
    __shared__ float regB[4160];
    __shared__ float sh4[4];
    float* h2f = regB;
    float* h1f = regA;
    float* xst = regA;
    const int bidx = blockIdx.x;
    const int t = threadIdx.x;
    const int wu = __builtin_amdgcn_readfirstlane(t >> 6);
    const int l = t & 63;
    const int py = wu >> 1, px = wu & 1;

    if (t < 32) zs[t] = ztL[(size_t)bidx * 64 + 32 + t];
    {
        float4 z4 = make_float4(0.f, 0.f, 0.f, 0.f);
        for (int e = t; e < 900; e += 256) ((float4*)regA)[e] = z4;
    }
    __syncthreads();

    // ---- P1: h1 = relu(M1 @ z_s + c1) ----
    {
        float acc[8];
        #pragma unroll
        for (int j = 0; j < 8; j++) acc[j] = c1L[j * 256 + t];
        const float4* M14 = (const float4*)M1L;
        #pragma unroll
        for (int q4 = 0; q4 < 8; q4++) {
            float4 z4 = *(const float4*)(zs + q4 * 4);
            #pragma unroll
            for (int j = 0; j < 8; j++) {
                float4 m = M14[(j * 8 + q4) * 256 + t];
                acc[j] = fmaf(z4.x, m.x, fmaf(z4.y, m.y, fmaf(z4.z, m.z, fmaf(z4.w, m.w, acc[j]))));
            }
        }
        int p = t & 63, ocg = t >> 6;
        int y = p >> 3, x = p & 7;
        float* hp = h1f + (y + 1) * 360 + (x + 1) * 36 + ocg * 8;
        float4 r0, r1;
        r0.x = fmaxf(acc[0], 0.f); r0.y = fmaxf(acc[1], 0.f);
        r0.z = fmaxf(acc[2], 0.f); r0.w = fmaxf(acc[3], 0.f);
        r1.x = fmaxf(acc[4], 0.f); r1.y = fmaxf(acc[5], 0.f);
        r1.z = fmaxf(acc[6], 0.f); r1.w = fmaxf(acc[7], 0.f);
        *(float4*)(hp)     = r0;
        *(float4*)(hp + 4) = r1;
    }
    __syncthreads();

    // ---- deconv2 ----
    {
        int a = l >> 3, b = l & 7;
        float acc[16];
        #pragma unroll
        for (int j = 0; j < 16; j++) acc[j] = d2[j];
        #pragma unroll
        for (int sy = 0; sy < 2; sy++) {
            int ky = py + 2 * sy;
            int iyf = a + py + sy - 1;
            #pragma unroll
            for (int sx = 0; sx < 2; sx++) {
                int kx = px + 2 * sx;
                int ixf = b + px + sx - 1;
                const float4* ip4 = (const float4*)(h1f + (iyf + 1) * 360 + (ixf + 1) * 36);
                const float* wb = wt2 + (ky * 4 + kx) * 512;
                #pragma unroll 2
                for (int cc = 0; cc < 8; cc++) {
                    float4 v = ip4[cc];
                    float vv[4] = {v.x, v.y, v.z, v.w};
                    #pragma unroll
                    for (int r = 0; r < 4; r++) {
                        const float4* wq = (const float4*)(wb + (cc * 4 + r) * 16);
                        float4 w0 = wq[0], w1 = wq[1], w2 = wq[2], w3 = wq[3];
                        float vr = vv[r];
                        acc[0]  = fmaf(vr, w0.x, acc[0]);
                        acc[1]  = fmaf(vr, w0.y, acc[1]);
                        acc[2]  = fmaf(vr, w0.z, acc[2]);
                        acc[3]  = fmaf(vr, w0.w, acc[3]);
                        acc[4]  = fmaf(vr, w1.x, acc[4]);
                        acc[5]  = fmaf(vr, w1.y, acc[5]);
                        acc[6]  = fmaf(vr, w1.z, acc[6]);
                        acc[7]  = fmaf(vr, w1.w, acc[7]);
                        acc[8]  = fmaf(vr, w2.x, acc[8]);
                        acc[9]  = fmaf(vr, w2.y, acc[9]);
                        acc[10] = fmaf(vr, w2.z, acc[10]);
                        acc[11] = fmaf(vr, w2.w, acc[11]);
                        acc[12] = fmaf(vr, w3.x, acc[12]);
                        acc[13] = fmaf(vr, w3.y, acc[13]);
                        acc[14] = fmaf(vr, w3.z, acc[14]);
                        acc[15] = fmaf(vr, w3.w, acc[15]);
                    }
                }
            }
        }
        float* hq = h2f + (2 * a + py) * 260 + (2 * b + px) * 16;
        #pragma unroll
        for (int j = 0; j < 4; j++) {
            float4 r;
            r.x = fmaxf(acc[j*4+0], 0.f);
            r.y = fmaxf(acc[j*4+1], 0.f);
            r.z = fmaxf(acc[j*4+2], 0.f);
            r.w = fmaxf(acc[j*4+3], 0.f);
            *(float4*)(hq + j * 4) = r;
        }
    }
    __syncthreads();

    // ---- deconv3 ----
    {
        int oy2 = l >> 2, b3 = l & 3;
        float acc[4];
        float d30 = d3[0];
        #pragma unroll
        for (int k = 0; k < 4; k++) acc[k] = d30;
        #pragma unroll
        for (int sy = 0; sy < 2; sy++) {
            int ky = py + 2 * sy;
            int iy = oy2 + py + sy - 1;
            if ((unsigned)iy >= 16u) continue;
            #pragma unroll
            for (int sx = 0; sx < 2; sx++) {
                int kx = px + 2 * sx;
                int cx = px + sx - 1;
                const float* wvp = wt3 + (ky * 4 + kx) * 16;
                #pragma unroll
                for (int k = 0; k < 4; k++) {
                    int ix = b3 + 4 * k + cx;
                    if ((unsigned)ix >= 16u) continue;
                    const float4* in4 = (const float4*)(h2f + iy * 260 + ix * 16);
                    #pragma unroll
                    for (int cc = 0; cc < 4; cc++) {
                        float4 v = in4[cc];
                        float4 wq = ((const float4*)wvp)[cc];
                        acc[k] = fmaf(v.x, wq.x, acc[k]);
                        acc[k] = fmaf(v.y, wq.y, acc[k]);
                        acc[k] = fmaf(v.z, wq.z, acc[k]);
                        acc[k] = fmaf(v.w, wq.w, acc[k]);
                    }
                }
            }
        }
        int oy = 2 * oy2 + py;
        #pragma unroll
        for (int k = 0; k < 4; k++) {
            int ox = 2 * (b3 + 4 * k) + px;
            xst[oy * 36 + ox] = 1.f / (1.f + expf(-acc[k]));
        }
    }
    __syncthreads();

    // ---- coalesced Xrec write + X read + lhood ----
    {
        int row = t >> 3, col = (t & 7) * 4;
        float4 xr4 = *(const float4*)(xst + row * 36 + col);
        *(float4*)(Xrec + (size_t)bidx * 1024 + t * 4) = xr4;
        float4 xi4 = *(const float4*)(X + (size_t)bidx * 1024 + t * 4);
        float ll = 0.f;
        ll += logf(0.001f + xr4.x) * xi4.x + logf(1.001f - xr4.x) * (1.f - xi4.x);
        ll += logf(0.001f + xr4.y) * xi4.y + logf(1.001f - xr4.y) * (1.f - xi4.y);
        ll += logf(0.001f + xr4.z) * xi4.z + logf(1.001f - xr4.z) * (1.f - xi4.z);
        ll += logf(0.001f + xr4.w) * xi4.w + logf(1.001f - xr4.w) * (1.f - xi4.w);
        #pragma unroll
        for (int off = 32; off; off >>= 1) ll += __shfl_down(ll, off, 64);
        if ((t & 63) == 0) sh4[t >> 6] = ll;
    }
    __syncthreads();
    if (t == 0) atomicAdd(&lhood[bidx / T_S], sh4[0] + sh4[1] + sh4[2] + sh4[3]);
}

// ---------------- final scalars (+ kl_w fused) ----------------
__global__ __launch_bounds__(256) void final2(
    const float* __restrict__ lhood, const float* __restrict__ klz,
    const float* __restrict__ W1, const float* __restrict__ W2,
    const int* __restrict__ Ndata, float* __restrict__ outs)
{
    __shared__ float shA[4], shB[4], shC[4];
    int t = threadIdx.x;
    float a = lhood[t];
    float b = klz[t];
    float c = 0.f;
    for (int i = t; i < 64 * HDYN_S; i += 256) c = fmaf(W1[i], W1[i], c);
    for (int i = t; i < HDYN_S * Q_S; i += 256) c = fmaf(W2[i], W2[i], c);
    #pragma unroll
    for (int off = 32; off; off >>= 1) {
        a += __shfl_down(a, off, 64);
        b += __shfl_down(b, off, 64);
        c += __shfl_down(c, off, 64);
    }
    if ((t & 63) == 0) { shA[t >> 6] = a; shB[t >> 6] = b; shC[t >> 6] = c; }
    __syncthreads();
    if (t == 0) {
        float Nd = (float)Ndata[0];
        float lh = Nd * ((shA[0] + shA[1] + shA[2] + shA[3]) / 256.f);
        float kz = Nd * ((shB[0] + shB[1] + shB[2] + shB[3]) / 256.f);
        float bkw = 0.5f * (shC[0] + shC[1] + shC[2] + shC[3]);
        outs[0] = lh - kz - bkw;
        outs[1] = lh;
        outs[2] = kz;
        outs[3] = bkw;
    }
}

extern "C" void kernel_launch(void* const* d_in, const int* in_sizes, int n_in,
                              void* d_out, int out_size, void* d_ws, size_t ws_size,
                              hipStream_t stream) {
    const float* X      = (const float*)d_in[0];
    const float* eps_s0 = (const float*)d_in[1];
    const float* eps_v0 = (const float*)d_in[2];
    const float* Cs1 = (const float*)d_in[3],  *cs1 = (const float*)d_in[4];
    const float* Cs2 = (const float*)d_in[5],  *cs2 = (const float*)d_in[6];
    const float* Cs3 = (const float*)d_in[7],  *cs3 = (const float*)d_in[8];
    const float* Wsm = (const float*)d_in[9],  *bsm = (const float*)d_in[10];
    const float* Wsl = (const float*)d_in[11], *bsl = (const float*)d_in[12];
    const float* Cv1 = (const float*)d_in[13], *cv1 = (const float*)d_in[14];
    const float* Cv2 = (const float*)d_in[15], *cv2 = (const float*)d_in[16];
    const float* Cv3 = (const float*)d_in[17], *cv3 = (const float*)d_in[18];
    const float* Wvm = (const float*)d_in[19], *bvm = (const float*)d_in[20];
    const float* Wvl = (const float*)d_in[21], *bvl = (const float*)d_in[22];
    const float* W1  = (const float*)d_in[23], *b1  = (const float*)d_in[24];
    const float* W2  = (const float*)d_in[25], *b2  = (const float*)d_in[26];
    const float* Wf  = (const float*)d_in[27], *bf  = (const float*)d_in[28];
    const float* D1  = (const float*)d_in[29], *d1  = (const float*)d_in[30];
    const float* D2  = (const float*)d_in[31], *d2  = (const float*)d_in[32];
    const float* D3  = (const float*)d_in[33], *d3  = (const float*)d_in[34];
    const int*   Ndata = (const int*)d_in[35];

    float* out = (float*)d_out;
    float* ws  = (float*)d_ws;

    // s-chain scratch lives in the (currently dead) Xrec region of d_out
    float* a1s = out + OS_A1S;
    float* a2s = out + OS_A2S;
    float* a3s = out + OS_A3S;

    prep_enc<<<331, 256, 0, stream>>>(Cs1, Cv1, Cs2, Cv2, Cs3, Cv3, ws);

    // ---- both encoders, merged (z = 0: s / frame0, z = 1: v / 10 frames) ----
    conv1_both<<<dim3(256, 2, 2), 256, 0, stream>>>(X,
        ws + TC_S1, cs1, a1s,
        ws + TC_V1, cv1, ws + WS_A1V);
    conv2_both<<<dim3(256, 2, 2), 256, 0, stream>>>(
        a1s, ws + TC_S2, cs2, a2s,
        ws + WS_A1V, ws + TC_V2, cv2, ws + WS_A2V);
    conv3_both<<<dim3(256, 2, 2), 256, 0, stream>>>(
        a2s, ws + TC_S3, cs3, a3s,
        ws + WS_A2V, ws + TC_V3, cv3, ws + WS_A3V);
    fc_both<<<512, 256, 0, stream>>>(a3s, ws + WS_A3V,
        Wsm, bsm, Wsl, bsl, Wvm, bvm, Wvl, bvl,
        ws + WS_S0MU, ws + WS_S0LV, ws + WS_V0MU, ws + WS_V0LV);

    // ---- reparam + M1 compose + D2/D3 transposes (A1V/A2V/A3V now dead) ----
    reparam_prep<<<256, 256, 0, stream>>>(ws + WS_S0MU, ws + WS_S0LV, ws + WS_V0MU, ws + WS_V0LV,
                                          eps_s0, eps_v0, Wf, bf, D1, d1, D2, D3, ws,
                                          out + OUT_QM, out + OUT_QLV,
                                          out + OUT_ZT, ws + WS_LOGP);

    // ---- RK4 ODE (+ klz folded) ----
    ode_kernel<<<256, 256, 0, stream>>>(W1, b1, W2, b2, out + OUT_ZT, ws + WS_LOGP,
                                        ws + WS_KLZ);

    // ---- fused decoder ----
    decoder5<<<5120, 256, 0, stream>>>(out + OUT_ZT, ws + WS_M1, ws + WS_C1,
                                       ws + WS_WT2, d2, ws + WS_WT3, d3,
                                       X, out + OUT_XREC, ws + WS_LHOOD);

    // ---- final scalars ----
    final2<<<1, 256, 0, stream>>>(ws + WS_LHOOD, ws + WS_KLZ, W1, W2, Ndata,
                                  out + OUT_SCAL);
}

// Round 4
// 488.613 us; speedup vs baseline: 1.2474x; 1.0137x over previous
//
#include <hip/hip_runtime.h>
#include <math.h>

#define N_S 256
#define T_S 20
#define D_S 32
#define NF_S 16
#define Q_S 32
#define HDYN_S 256
#define HDIM_S 1024
#define VSTEPS_S 10
#define DT_S 0.1f
#define LOG2PI_F 1.8378770664093453f

// ---- d_out offsets (floats) ----
#define OUT_XREC 0
#define OUT_QM   5242880
#define OUT_QLV  5259264
#define OUT_ZT   5275648
#define OUT_SCAL 5603328

// ---- d_out scratch (inside XREC region, dead until decoder5) ----
#define OS_A1S   0          // 1048576 (s conv1 out)
#define OS_A2S   1048576    // 524288  (s conv2 out)

// ---- workspace offsets (floats) ----
#define WS_A1V   0          // 1048576 (v conv1 out; dead after conv2)
#define WS_WT2   32768      // 8192   (written by ode compose blocks, over dead A1V)
#define WS_WT3   40960      // 256
#define WS_A2V   1048576    // 524288 (v conv2 out; dead after conv3fc)
#define WS_M1    1048576    // 65536  (written by ode compose blocks, over dead A2V)
#define WS_C1    1114112    // 2048
#define WS_S0MU  1572864    // 8192 (atomic targets, zeroed in prep_enc)
#define WS_S0LV  1581056
#define WS_V0MU  1589248
#define WS_V0LV  1597440
#define WS_LHOOD 1610752
#define WS_KLZ   1611008
#define WS_TC    1611520
#define TC_S1 (WS_TC + 0)
#define TC_V1 (WS_TC + 256)
#define TC_S2 (WS_TC + 2816)
#define TC_V2 (WS_TC + 11008)
#define TC_S3 (WS_TC + 19200)
#define TC_V3 (WS_TC + 51968)

// ---------------- weight transposes ----------------
__device__ inline void enc_tr(const float* __restrict__ src, float* __restrict__ dst,
                              int e, int CI, int CO) {
    int co = e % CO; int r = e / CO; int tap = r & 15; int ci = r >> 4;
    dst[e] = src[(co * CI + ci) * 16 + tap];
}
__device__ inline void dec_tr(const float* __restrict__ src, float* __restrict__ dst,
                              int e, int CI, int CO) {
    int co = e % CO; int r = e / CO; int ci = r % CI; int tap = r / CI;
    dst[e] = src[(co * CI + ci) * 16 + tap];
}

// prep: weight transposes + zero lhood + zero mu/lv atomic targets
__global__ __launch_bounds__(256) void prep_enc(
    const float* __restrict__ Cs1, const float* __restrict__ Cv1,
    const float* __restrict__ Cs2, const float* __restrict__ Cv2,
    const float* __restrict__ Cs3, const float* __restrict__ Cv3,
    float* __restrict__ ws)
{
    int blk = blockIdx.x, t = threadIdx.x;
    if (blk < 331) {
        int idx = blk * 256 + t;
        if (blk == 0) ws[WS_LHOOD + t] = 0.f;
        if (idx < 256)        enc_tr(Cs1, ws + TC_S1, idx,          1, 16);
        else if (idx < 2816)  enc_tr(Cv1, ws + TC_V1, idx - 256,   10, 16);
        else if (idx < 11008) enc_tr(Cs2, ws + TC_S2, idx - 2816,  16, 32);
        else if (idx < 19200) enc_tr(Cv2, ws + TC_V2, idx - 11008, 16, 32);
        else if (idx < 51968) enc_tr(Cs3, ws + TC_S3, idx - 19200, 32, 64);
        else if (idx < 84736) enc_tr(Cv3, ws + TC_V3, idx - 51968, 32, 64);
    } else {
        // zero S0MU/S0LV/V0MU/V0LV (contiguous 32768 floats)
        int zi = (blk - 331) * 256 + t;
        ws[WS_S0MU + zi] = 0.f;
    }
}

// ---------------- conv1 both encoders: z=0 -> s (cin=1), z=1 -> v (cin=10) ------------
__global__ __launch_bounds__(256) void conv1_both(
    const float* __restrict__ x,
    const float* __restrict__ wts, const float* __restrict__ bs, float* __restrict__ outs,
    const float* __restrict__ wtv, const float* __restrict__ bv, float* __restrict__ outv)
{
    __shared__ float xin[10 * 630];
    int sel = blockIdx.z;
    int cin = sel ? 10 : 1;
    const float* wt = sel ? wtv : wts;
    const float* bias = sel ? bv : bs;
    float* out = sel ? outv : outs;

    int b = blockIdx.x, yh = blockIdx.y, t = threadIdx.x;
    for (int e = t; e < cin * 576; e += 256) {
        int ci = e / 576;
        int r = (e >> 5) - ci * 18;
        int cx = e & 31;
        int gy = yh * 16 - 1 + r;
        float v = (gy >= 0 && gy < 32) ? x[(size_t)b * 20480 + ci * 1024 + gy * 32 + cx] : 0.f;
        xin[ci * 630 + r * 35 + cx + 1] = v;
    }
    for (int e = t; e < cin * 18; e += 256) {
        int ci = e / 18, r = e - ci * 18;
        xin[ci * 630 + r * 35 + 0] = 0.f;
        xin[ci * 630 + r * 35 + 33] = 0.f;
    }
    __syncthreads();

    int ocq = __builtin_amdgcn_readfirstlane(t >> 7);
    int p = t & 127;
    int oyl = p >> 4, ox = p & 15;
    const float* wg = wt + ocq * 8;
    float acc[8];
    #pragma unroll
    for (int j = 0; j < 8; j++) acc[j] = bias[ocq * 8 + j];
    for (int ci = 0; ci < cin; ci++) {
        const float* xc = xin + ci * 630;
        const float* wc = wg + ci * 256;
        #pragma unroll
        for (int ky = 0; ky < 4; ky++) {
            const float* xr = xc + (2 * oyl + ky) * 35;
            #pragma unroll
            for (int kx = 0; kx < 4; kx++) {
                float v = xr[2 * ox + kx];
                const float4* w4 = (const float4*)(wc + (ky * 4 + kx) * 16);
                float4 wa = w4[0], wb2 = w4[1];
                acc[0] = fmaf(v, wa.x, acc[0]);
                acc[1] = fmaf(v, wa.y, acc[1]);
                acc[2] = fmaf(v, wa.z, acc[2]);
                acc[3] = fmaf(v, wa.w, acc[3]);
                acc[4] = fmaf(v, wb2.x, acc[4]);
                acc[5] = fmaf(v, wb2.y, acc[5]);
                acc[6] = fmaf(v, wb2.z, acc[6]);
                acc[7] = fmaf(v, wb2.w, acc[7]);
            }
        }
    }
    int oy = yh * 8 + oyl;
    size_t ob = (size_t)b * 4096 + (size_t)(ocq * 8) * 256 + oy * 16 + ox;
    #pragma unroll
    for (int j = 0; j < 8; j++) out[ob + (size_t)j * 256] = fmaxf(acc[j], 0.f);
}

// ---------------- conv2 both: z selects encoder; y = oc-half; scalar weights ----------
__global__ __launch_bounds__(256) void conv2_both(
    const float* __restrict__ a1s, const float* __restrict__ wts, const float* __restrict__ bsb,
    float* __restrict__ outs,
    const float* __restrict__ a1v, const float* __restrict__ wtv, const float* __restrict__ bvb,
    float* __restrict__ outv)
{
    __shared__ float xin[16 * 272];
    int sel = blockIdx.z;
    const float* a1 = sel ? a1v : a1s;
    const float* wt = sel ? wtv : wts;
    const float* bias = sel ? bvb : bsb;
    float* out = sel ? outv : outs;

    int b = blockIdx.x, h = blockIdx.y, t = threadIdx.x;
    for (int e = t; e < 4096; e += 256) {
        int ci = e >> 8, r = e & 255, iy = r >> 4, ix = r & 15;
        xin[ci * 272 + iy * 17 + ix] = a1[(size_t)b * 4096 + e];
    }
    __syncthreads();

    int ocq = __builtin_amdgcn_readfirstlane(t >> 6);
    int p = t & 63;
    int pa = p >> 3, pb = p & 7;
    int hbase = h * 16 + ocq * 4;
    float acc[4];
    #pragma unroll
    for (int j = 0; j < 4; j++) acc[j] = bias[hbase + j];
    for (int ci = 0; ci < 16; ci++) {
        const float* xc = xin + ci * 272;
        const float* wc = wt + ci * 512 + hbase;
        #pragma unroll
        for (int ky = 0; ky < 4; ky++) {
            int iy = 2 * pa - 1 + ky;
            if ((unsigned)iy >= 16u) continue;
            const float* xr = xc + iy * 17;
            #pragma unroll
            for (int kx = 0; kx < 4; kx++) {
                int ix = 2 * pb - 1 + kx;
                if ((unsigned)ix >= 16u) continue;
                float v = xr[ix];
                float4 wv = *(const float4*)(wc + (ky * 4 + kx) * 32);
                acc[0] = fmaf(v, wv.x, acc[0]);
                acc[1] = fmaf(v, wv.y, acc[1]);
                acc[2] = fmaf(v, wv.z, acc[2]);
                acc[3] = fmaf(v, wv.w, acc[3]);
            }
        }
    }
    size_t ob = (size_t)b * 2048 + (size_t)(hbase) * 64 + pa * 8 + pb;
    #pragma unroll
    for (int j = 0; j < 4; j++) out[ob + (size_t)j * 64] = fmaxf(acc[j], 0.f);
}

// ---------------- conv3 + encoder-FC fused (atomic partial GEMV) ----------------
// Block (b, h, sel): computes h-chunk [h*512, h*512+512) of the flattened conv3
// output, keeps it in LDS, then accumulates its contribution to mu/lv via one
// atomicAdd per output (2 blocks contribute per target). Bias added in ode.
__global__ __launch_bounds__(256) void conv3fc_both(
    const float* __restrict__ a2s, const float* __restrict__ wts,
    const float* __restrict__ bsb,
    const float* __restrict__ Wsm, const float* __restrict__ Wsl,
    float* __restrict__ mus, float* __restrict__ lvs,
    const float* __restrict__ a2v, const float* __restrict__ wtv,
    const float* __restrict__ bvb,
    const float* __restrict__ Wvm, const float* __restrict__ Wvl,
    float* __restrict__ muv, float* __restrict__ lvv)
{
    __shared__ float xin[32 * 72];
    __shared__ float wl[16384];
    __shared__ float bl[32];
    __shared__ float hbuf[512];
    __shared__ float pr[256];
    int sel = blockIdx.z;
    const float* a2 = sel ? a2v : a2s;
    const float* wt = sel ? wtv : wts;
    const float* bias = sel ? bvb : bsb;

    int b = blockIdx.x, h = blockIdx.y, t = threadIdx.x;
    for (int e = t; e < 2048; e += 256) {
        int ci = e >> 6, r = e & 63, iy = r >> 3, ix = r & 7;
        xin[ci * 72 + iy * 9 + ix] = a2[(size_t)b * 2048 + e];
    }
    for (int e4 = t; e4 < 4096; e4 += 256) {
        int grp = e4 >> 3, c4 = e4 & 7;
        ((float4*)wl)[e4] = ((const float4*)(wt + grp * 64 + h * 32))[c4];
    }
    if (t < 32) bl[t] = bias[h * 32 + t];
    __syncthreads();

    int ocq = t >> 4, p = t & 15;
    int pa = p >> 2, pb = p & 3;
    float a0 = bl[ocq * 2], a1 = bl[ocq * 2 + 1];
    for (int ci = 0; ci < 32; ci++) {
        const float* xc = xin + ci * 72;
        const float* wc = wl + ci * 512 + ocq * 2;
        #pragma unroll
        for (int ky = 0; ky < 4; ky++) {
            int iy = 2 * pa - 1 + ky;
            if ((unsigned)iy >= 8u) continue;
            const float* xr = xc + iy * 9;
            #pragma unroll
            for (int kx = 0; kx < 4; kx++) {
                int ix = 2 * pb - 1 + kx;
                if ((unsigned)ix >= 8u) continue;
                float v = xr[ix];
                float2 wv = *(const float2*)(wc + (ky * 4 + kx) * 32);
                a0 = fmaf(v, wv.x, a0);
                a1 = fmaf(v, wv.y, a1);
            }
        }
    }
    int lp_ = ocq * 32 + p;           // (oc_local)*16 + pos, oc_local = 2*ocq(+1)
    hbuf[lp_]      = fmaxf(a0, 0.f);
    hbuf[lp_ + 16] = fmaxf(a1, 0.f);
    __syncthreads();

    // ---- fc partial: q = t&63 (0..31 -> mu, 32..63 -> lv), c = k-chunk ----
    {
        int q = t & 63, c = t >> 6, qq = q & 31;
        const float* Wb = (q < 32) ? (sel ? Wvm : Wsm) : (sel ? Wvl : Wsl);
        const float* wp = Wb + (size_t)(h * 512 + c * 128) * 32 + qq;
        const float* hp = hbuf + c * 128;
        float s = 0.f;
        #pragma unroll 4
        for (int k = 0; k < 128; k++) s = fmaf(hp[k], wp[(size_t)k * 32], s);
        pr[c * 64 + q] = s;
    }
    __syncthreads();
    if (t < 64) {
        float s = (pr[t] + pr[64 + t]) + (pr[128 + t] + pr[192 + t]);
        float* dst = (t < 32) ? (sel ? muv : mus) : (sel ? lvv : lvs);
        atomicAdd(&dst[b * 32 + (t & 31)], s);
    }
}

// ---------------- RK4 ODE + reparam prologue + klz + (compose blocks) ----------------
// blocks 0..255: sample n (reparam -> RK4 -> klz)
// blocks 256..319: M1 compose; 320..335: c1; 336..368: WT2/WT3 transposes
__global__ __launch_bounds__(256) void ode_kernel(
    const float* __restrict__ W1, const float* __restrict__ b1,
    const float* __restrict__ W2, const float* __restrict__ b2,
    const float* __restrict__ s0mu_a, const float* __restrict__ s0lv_a,
    const float* __restrict__ v0mu_a, const float* __restrict__ v0lv_a,
    const float* __restrict__ bsm, const float* __restrict__ bsl,
    const float* __restrict__ bvm, const float* __restrict__ bvl,
    const float* __restrict__ eps_s, const float* __restrict__ eps_v,
    const float* __restrict__ Wf, const float* __restrict__ bf,
    const float* __restrict__ D1, const float* __restrict__ d1,
    const float* __restrict__ D2, const float* __restrict__ D3,
    float* __restrict__ ws,
    float* __restrict__ qm, float* __restrict__ qlv,
    float* __restrict__ ztL, float* __restrict__ klz)
{
    __shared__ float W2s[HDYN_S * Q_S];
    __shared__ float zeval[64];
    __shared__ float hsh[HDYN_S];
    __shared__ float dvred[HDYN_S];
    __shared__ float red4[4];
    int n = blockIdx.x;
    int t = threadIdx.x;

    if (n >= 256) {
        // ---- compose blocks (overlapped under the serial ODE span) ----
        float* shA = W2s;
        float* shB = W2s + 4096;
        int m = n - 256;
        if (m < 64) {
            int j = m >> 3, q4 = m & 7;
            for (int e = t; e < 4096; e += 256) {
                int qq = e >> 10, k = e & 1023;
                shA[e] = Wf[(size_t)(q4 * 4 + qq) * 1024 + k];
            }
            for (int e = t; e < 4096; e += 256) {
                int ocg = e >> 10, r = e & 1023;
                shB[e] = D1[(size_t)(ocg * 8 + j) * 1024 + r];
            }
            __syncthreads();
            int p = t & 63, ocg = t >> 6;
            int y = p >> 3, x = p & 7;
            float acc[4] = {0.f, 0.f, 0.f, 0.f};
            #pragma unroll
            for (int sy = 0; sy < 2; sy++) {
                int ky = (y & 1) + 2 * sy;
                int iy = ((y + ky) >> 1) - 1;
                if ((unsigned)iy >= 4u) continue;
                #pragma unroll
                for (int sx = 0; sx < 2; sx++) {
                    int kx = (x & 1) + 2 * sx;
                    int ix = ((x + kx) >> 1) - 1;
                    if ((unsigned)ix >= 4u) continue;
                    const float* dl = shB + ocg * 1024 + ky * 4 + kx;
                    const float* wl = shA + iy * 4 + ix;
                    for (int ci = 0; ci < 64; ci++) {
                        float wv = dl[ci * 16];
                        int kb = ci * 16;
                        acc[0] = fmaf(wl[kb],        wv, acc[0]);
                        acc[1] = fmaf(wl[1024 + kb], wv, acc[1]);
                        acc[2] = fmaf(wl[2048 + kb], wv, acc[2]);
                        acc[3] = fmaf(wl[3072 + kb], wv, acc[3]);
                    }
                }
            }
            ((float4*)(ws + WS_M1))[m * 256 + t] = make_float4(acc[0], acc[1], acc[2], acc[3]);
        } else if (m < 80) {
            int bb = m - 64;
            for (int e = t; e < 1024; e += 256) shA[e] = bf[e];
            for (int e = t; e < 2048; e += 256) shB[e] = D1[(size_t)bb * 2048 + e];
            __syncthreads();
            int oidx = t >> 1, half = t & 1;
            int ocr = oidx >> 6, p = oidx & 63;
            int y = p >> 3, x = p & 7;
            float acc = 0.f;
            #pragma unroll
            for (int sy = 0; sy < 2; sy++) {
                int ky = (y & 1) + 2 * sy;
                int iy = ((y + ky) >> 1) - 1;
                if ((unsigned)iy >= 4u) continue;
                #pragma unroll
                for (int sx = 0; sx < 2; sx++) {
                    int kx = (x & 1) + 2 * sx;
                    int ix = ((x + kx) >> 1) - 1;
                    if ((unsigned)ix >= 4u) continue;
                    const float* dl = shB + ocr * 1024 + half * 512 + ky * 4 + kx;
                    const float* wl = shA + half * 512 + iy * 4 + ix;
                    for (int cc = 0; cc < 32; cc++)
                        acc = fmaf(wl[cc * 16], dl[cc * 16], acc);
                }
            }
            acc += __shfl_down(acc, 1, 64);
            if (half == 0) {
                int oc = bb * 2 + ocr;
                ws[WS_C1 + (oc & 7) * 256 + (oc >> 3) * 64 + p] = acc + d1[oc];
            }
        } else {
            int idx = (m - 80) * 256 + t;
            if (idx < 8192)      dec_tr(D2, ws + WS_WT2, idx,        32, 16);
            else if (idx < 8448) dec_tr(D3, ws + WS_WT3, idx - 8192, 16, 1);
        }
        return;
    }

    // ---- sample path ----
    for (int i = t; i < HDYN_S * Q_S; i += 256) W2s[i] = W2[i];
    float w1r[64];
    #pragma unroll
    for (int j = 0; j < 64; j++) w1r[j] = W1[j * HDYN_S + t];
    float b1r = b1[t];
    __syncthreads();
    float ck = 0.f;
    #pragma unroll
    for (int i = 0; i < Q_S; i++) ck = fmaf(w1r[i], W2s[t * Q_S + i], ck);

    size_t zoff = (size_t)n * T_S * 64;
    float zj = 0.f, ksumj = 0.f, zevalj = 0.f, lp = 0.f, lsum = 0.f, klacc = 0.f;

    // ---- reparam prologue (folded) ----
    if (t < 64) {
        int q = t & 31;
        float mu, lvv2, ep;
        if (t < 32) { mu = v0mu_a[n*32+q] + bvm[q]; lvv2 = v0lv_a[n*32+q] + bvl[q]; ep = eps_v[n*32+q]; }
        else        { mu = s0mu_a[n*32+q] + bsm[q]; lvv2 = s0lv_a[n*32+q] + bsl[q]; ep = eps_s[n*32+q]; }
        float zv = fmaf(ep, expf(lvv2), mu);
        qm[n*64 + t]  = mu;
        qlv[n*64 + t] = lvv2;
        zj = zv; zevalj = zv; zeval[t] = zv;
        ztL[zoff + t] = zv;
        float e2 = ep * ep;
        float z2 = zv * zv;
        #pragma unroll
        for (int off = 32; off; off >>= 1) {
            e2 += __shfl_down(e2, off, 64);
            z2 += __shfl_down(z2, off, 64);
        }
        if (t == 0) {
            lp = -0.5f * e2 - Q_S * LOG2PI_F;
            klacc = lp - (-0.5f * z2 - Q_S * LOG2PI_F);
        }
    }

    const float wc[4] = {1.f, 2.f, 2.f, 1.f};
    const float ac[3] = {0.5f * DT_S, 0.5f * DT_S, DT_S};
    const float4* ze4 = (const float4*)zeval;

    for (int step = 1; step < T_S; step++) {
        for (int e = 0; e < 4; e++) {
            __syncthreads();
            float p0 = 0.f, p1 = 0.f, p2 = 0.f, p3 = 0.f;
            #pragma unroll
            for (int j4 = 0; j4 < 4; j4++) {
                float4 za = ze4[j4], zb = ze4[4 + j4], zc = ze4[8 + j4], zd = ze4[12 + j4];
                p0 = fmaf(za.x, w1r[j4*4+0], p0);
                p0 = fmaf(za.y, w1r[j4*4+1], p0);
                p0 = fmaf(za.z, w1r[j4*4+2], p0);
                p0 = fmaf(za.w, w1r[j4*4+3], p0);
                p1 = fmaf(zb.x, w1r[16+j4*4+0], p1);
                p1 = fmaf(zb.y, w1r[16+j4*4+1], p1);
                p1 = fmaf(zb.z, w1r[16+j4*4+2], p1);
                p1 = fmaf(zb.w, w1r[16+j4*4+3], p1);
                p2 = fmaf(zc.x, w1r[32+j4*4+0], p2);
                p2 = fmaf(zc.y, w1r[32+j4*4+1], p2);
                p2 = fmaf(zc.z, w1r[32+j4*4+2], p2);
                p2 = fmaf(zc.w, w1r[32+j4*4+3], p2);
                p3 = fmaf(zd.x, w1r[48+j4*4+0], p3);
                p3 = fmaf(zd.y, w1r[48+j4*4+1], p3);
                p3 = fmaf(zd.z, w1r[48+j4*4+2], p3);
                p3 = fmaf(zd.w, w1r[48+j4*4+3], p3);
            }
            float pre = b1r + ((p0 + p1) + (p2 + p3));
            float hk = tanhf(pre);
            hsh[t] = hk;
            float gk = (1.f - hk * hk) * ck;
            #pragma unroll
            for (int off = 32; off; off >>= 1) gk += __shfl_down(gk, off, 64);
            if ((t & 63) == 0) red4[t >> 6] = gk;
            __syncthreads();
            {
                int i = t & 31, p = t >> 5;
                const float4* h4 = (const float4*)(hsh + p * 32);
                float a0 = 0.f, a1 = 0.f;
                #pragma unroll
                for (int kk4 = 0; kk4 < 4; kk4++) {
                    float4 ha = h4[kk4];
                    float4 hb2 = h4[4 + kk4];
                    int kb = p * 32 + kk4 * 4;
                    a0 = fmaf(ha.x, W2s[(kb+0)*Q_S + i], a0);
                    a0 = fmaf(ha.y, W2s[(kb+1)*Q_S + i], a0);
                    a0 = fmaf(ha.z, W2s[(kb+2)*Q_S + i], a0);
                    a0 = fmaf(ha.w, W2s[(kb+3)*Q_S + i], a0);
                    int kc = kb + 16;
                    a1 = fmaf(hb2.x, W2s[(kc+0)*Q_S + i], a1);
                    a1 = fmaf(hb2.y, W2s[(kc+1)*Q_S + i], a1);
                    a1 = fmaf(hb2.z, W2s[(kc+2)*Q_S + i], a1);
                    a1 = fmaf(hb2.w, W2s[(kc+3)*Q_S + i], a1);
                }
                dvred[t] = a0 + a1;
            }
            __syncthreads();
            if (t < 64) {
                float tr = red4[0] + red4[1] + red4[2] + red4[3];
                float zv_shfl = __shfl(zevalj, (t >= 32) ? (t - 32) : t, 64);
                float kzv;
                if (t < 32) {
                    float dvi = b2[t];
                    #pragma unroll
                    for (int p = 0; p < 8; p++) dvi += dvred[p * 32 + t];
                    kzv = dvi;
                } else kzv = zv_shfl;
                if (e == 0) ksumj = kzv; else ksumj = fmaf(wc[e], kzv, ksumj);
                if (t == 0) { float kl = -tr; lsum = (e == 0) ? kl : fmaf(wc[e], kl, lsum); }
                if (e < 3) {
                    zevalj = fmaf(ac[e], kzv, zj);
                    zeval[t] = zevalj;
                } else {
                    zj = fmaf(DT_S / 6.f, ksumj, zj);
                    zevalj = zj; zeval[t] = zj;
                    ztL[zoff + step * 64 + t] = zj;
                    if (t == 0) lp = fmaf(DT_S / 6.f, lsum, lp);
                    float z2 = zj * zj;
                    #pragma unroll
                    for (int off = 32; off; off >>= 1) z2 += __shfl_down(z2, off, 64);
                    if (t == 0) klacc += lp - (-0.5f * z2 - Q_S * LOG2PI_F);
                }
            }
        }
    }
    if (t == 0) klz[n] = klacc;
}

// ---------------- fused decoder (unchanged from R3) ----------------
__global__ __launch_bounds__(256) void decoder5(
    const float* __restrict__ ztL, const float* __restrict__ M1L, const float* __restrict__ c1L,
    const float* __restrict__ wt2, const float* __restrict__ d2,
    const float* __restrict__ wt3, const float* __restrict__ d3,
    const float* __restrict__ X, float* __restrict__ Xrec, float* __restrict__ lhood)
{
    __shared__ float zs[32];
    __shared__ float regA[3600];
    __shared__ float regB[4160];
    __shared__ float sh4[4];
    float* h2f = regB;
    float* h1f = regA;
    float* xst = regA;
    const int bidx = blockIdx.x;
    const int t = threadIdx.x;
    const int wu = __builtin_amdgcn_readfirstlane(t >> 6);
    const int l = t & 63;
    const int py = wu >> 1, px = wu & 1;

    if (t < 32) zs[t] = ztL[(size_t)bidx * 64 + 32 + t];
    {
        float4 z4 = make_float4(0.f, 0.f, 0.f, 0.f);
        for (int e = t; e < 900; e += 256) ((float4*)regA)[e] = z4;
    }
    __syncthreads();

    // ---- P1: h1 = relu(M1 @ z_s + c1) ----
    {
        float acc[8];
        #pragma unroll
        for (int j = 0; j < 8; j++) acc[j] = c1L[j * 256 + t];
        const float4* M14 = (const float4*)M1L;
        #pragma unroll
        for (int q4 = 0; q4 < 8; q4++) {
            float4 z4 = *(const float4*)(zs + q4 * 4);
            #pragma unroll
            for (int j = 0; j < 8; j++) {
                float4 m = M14[(j * 8 + q4) * 256 + t];
                acc[j] = fmaf(z4.x, m.x, fmaf(z4.y, m.y, fmaf(z4.z, m.z, fmaf(z4.w, m.w, acc[j]))));
            }
        }
        int p = t & 63, ocg = t >> 6;
        int y = p >> 3, x = p & 7;
        float* hp = h1f + (y + 1) * 360 + (x + 1) * 36 + ocg * 8;
        float4 r0, r1;
        r0.x = fmaxf(acc[0], 0.f); r0.y = fmaxf(acc[1], 0.f);
        r0.z = fmaxf(acc[2], 0.f); r0.w = fmaxf(acc[3], 0.f);
        r1.x = fmaxf(acc[4], 0.f); r1.y = fmaxf(acc[5], 0.f);
        r1.z = fmaxf(acc[6], 0.f); r1.w = fmaxf(acc[7], 0.f);
        *(float4*)(hp)     = r0;
        *(float4*)(hp + 4) = r1;
    }
    __syncthreads();

    // ---- deconv2 ----
    {
        int a = l >> 3, b = l & 7;
        float acc[16];
        #pragma unroll
        for (int j = 0; j < 16; j++) acc[j] = d2[j];
        #pragma unroll
        for (int sy = 0; sy < 2; sy++) {
            int ky = py + 2 * sy;
            int iyf = a + py + sy - 1;
            #pragma unroll
            for (int sx = 0; sx < 2; sx++) {
                int kx = px + 2 * sx;
                int ixf = b + px + sx - 1;
                const float4* ip4 = (const float4*)(h1f + (iyf + 1) * 360 + (ixf + 1) * 36);
                const float* wb = wt2 + (ky * 4 + kx) * 512;
                #pragma unroll 2
                for (int cc = 0; cc < 8; cc++) {
                    float4 v = ip4[cc];
                    float vv[4] = {v.x, v.y, v.z, v.w};
                    #pragma unroll
                    for (int r = 0; r < 4; r++) {
                        const float4* wq = (const float4*)(wb + (cc * 4 + r) * 16);
                        float4 w0 = wq[0], w1 = wq[1], w2 = wq[2], w3 = wq[3];
                        float vr = vv[r];
                        acc[0]  = fmaf(vr, w0.x, acc[0]);
                        acc[1]  = fmaf(vr, w0.y, acc[1]);
                        acc[2]  = fmaf(vr, w0.z, acc[2]);
                        acc[3]  = fmaf(vr, w0.w, acc[3]);
                        acc[4]  = fmaf(vr, w1.x, acc[4]);
                        acc[5]  = fmaf(vr, w1.y, acc[5]);
                        acc[6]  = fmaf(vr, w1.z, acc[6]);
                        acc[7]  = fmaf(vr, w1.w, acc[7]);
                        acc[8]  = fmaf(vr, w2.x, acc[8]);
                        acc[9]  = fmaf(vr, w2.y, acc[9]);
                        acc[10] = fmaf(vr, w2.z, acc[10]);
                        acc[11] = fmaf(vr, w2.w, acc[11]);
                        acc[12] = fmaf(vr, w3.x, acc[12]);
                        acc[13] = fmaf(vr, w3.y, acc[13]);
                        acc[14] = fmaf(vr, w3.z, acc[14]);
                        acc[15] = fmaf(vr, w3.w, acc[15]);
                    }
                }
            }
        }
        float* hq = h2f + (2 * a + py) * 260 + (2 * b + px) * 16;
        #pragma unroll
        for (int j = 0; j < 4; j++) {
            float4 r;
            r.x = fmaxf(acc[j*4+0], 0.f);
            r.y = fmaxf(acc[j*4+1], 0.f);
            r.z = fmaxf(acc[j*4+2], 0.f);
            r.w = fmaxf(acc[j*4+3], 0.f);
            *(float4*)(hq + j * 4) = r;
        }
    }
    __syncthreads();

    // ---- deconv3 ----
    {
        int oy2 = l >> 2, b3 = l & 3;
        float acc[4];
        float d30 = d3[0];
        #pragma unroll
        for (int k = 0; k < 4; k++) acc[k] = d30;
        #pragma unroll
        for (int sy = 0; sy < 2; sy++) {
            int ky = py + 2 * sy;
            int iy = oy2 + py + sy - 1;
            if ((unsigned)iy >= 16u) continue;
            #pragma unroll
            for (int sx = 0; sx < 2; sx++) {
                int kx = px + 2 * sx;
                int cx = px + sx - 1;
                const float* wvp = wt3 + (ky * 4 + kx) * 16;
                #pragma unroll
                for (int k = 0; k < 4; k++) {
                    int ix = b3 + 4 * k + cx;
                    if ((unsigned)ix >= 16u) continue;
                    const float4* in4 = (const float4*)(h2f + iy * 260 + ix * 16);
                    #pragma unroll
                    for (int cc = 0; cc < 4; cc++) {
                        float4 v = in4[cc];
                        float4 wq = ((const float4*)wvp)[cc];
                        acc[k] = fmaf(v.x, wq.x, acc[k]);
                        acc[k] = fmaf(v.y, wq.y, acc[k]);
                        acc[k] = fmaf(v.z, wq.z, acc[k]);
                        acc[k] = fmaf(v.w, wq.w, acc[k]);
                    }
                }
            }
        }
        int oy = 2 * oy2 + py;
        #pragma unroll
        for (int k = 0; k < 4; k++) {
            int ox = 2 * (b3 + 4 * k) + px;
            xst[oy * 36 + ox] = 1.f / (1.f + expf(-acc[k]));
        }
    }
    __syncthreads();

    // ---- coalesced Xrec write + X read + lhood ----
    {
        int row = t >> 3, col = (t & 7) * 4;
        float4 xr4 = *(const float4*)(xst + row * 36 + col);
        *(float4*)(Xrec + (size_t)bidx * 1024 + t * 4) = xr4;
        float4 xi4 = *(const float4*)(X + (size_t)bidx * 1024 + t * 4);
        float ll = 0.f;
        ll += logf(0.001f + xr4.x) * xi4.x + logf(1.001f - xr4.x) * (1.f - xi4.x);
        ll += logf(0.001f + xr4.y) * xi4.y + logf(1.001f - xr4.y) * (1.f - xi4.y);
        ll += logf(0.001f + xr4.z) * xi4.z + logf(1.001f - xr4.z) * (1.f - xi4.z);
        ll += logf(0.001f + xr4.w) * xi4.w + logf(1.001f - xr4.w) * (1.f - xi4.w);
        #pragma unroll
        for (int off = 32; off; off >>= 1) ll += __shfl_down(ll, off, 64);
        if ((t & 63) == 0) sh4[t >> 6] = ll;
    }
    __syncthreads();
    if (t == 0) atomicAdd(&lhood[bidx / T_S], sh4[0] + sh4[1] + sh4[2] + sh4[3]);
}

// ---------------- final scalars (+ kl_w fused) ----------------
__global__ __launch_bounds__(256) void final2(
    const float* __restrict__ lhood, const float* __restrict__ klz,
    const float* __restrict__ W1, const float* __restrict__ W2,
    const int* __restrict__ Ndata, float* __restrict__ outs)
{
    __shared__ float shA[4], shB[4], shC[4];
    int t = threadIdx.x;
    float a = lhood[t];
    float b = klz[t];
    float c = 0.f;
    for (int i = t; i < 64 * HDYN_S; i += 256) c = fmaf(W1[i], W1[i], c);
    for (int i = t; i < HDYN_S * Q_S; i += 256) c = fmaf(W2[i], W2[i], c);
    #pragma unroll
    for (int off = 32; off; off >>= 1) {
        a += __shfl_down(a, off, 64);
        b += __shfl_down(b, off, 64);
        c += __shfl_down(c, off, 64);
    }
    if ((t & 63) == 0) { shA[t >> 6] = a; shB[t >> 6] = b; shC[t >> 6] = c; }
    __syncthreads();
    if (t == 0) {
        float Nd = (float)Ndata[0];
        float lh = Nd * ((shA[0] + shA[1] + shA[2] + shA[3]) / 256.f);
        float kz = Nd * ((shB[0] + shB[1] + shB[2] + shB[3]) / 256.f);
        float bkw = 0.5f * (shC[0] + shC[1] + shC[2] + shC[3]);
        outs[0] = lh - kz - bkw;
        outs[1] = lh;
        outs[2] = kz;
        outs[3] = bkw;
    }
}

extern "C" void kernel_launch(void* const* d_in, const int* in_sizes, int n_in,
                              void* d_out, int out_size, void* d_ws, size_t ws_size,
                              hipStream_t stream) {
    const float* X      = (const float*)d_in[0];
    const float* eps_s0 = (const float*)d_in[1];
    const float* eps_v0 = (const float*)d_in[2];
    const float* Cs1 = (const float*)d_in[3],  *cs1 = (const float*)d_in[4];
    const float* Cs2 = (const float*)d_in[5],  *cs2 = (const float*)d_in[6];
    const float* Cs3 = (const float*)d_in[7],  *cs3 = (const float*)d_in[8];
    const float* Wsm = (const float*)d_in[9],  *bsm = (const float*)d_in[10];
    const float* Wsl = (const float*)d_in[11], *bsl = (const float*)d_in[12];
    const float* Cv1 = (const float*)d_in[13], *cv1 = (const float*)d_in[14];
    const float* Cv2 = (const float*)d_in[15], *cv2 = (const float*)d_in[16];
    const float* Cv3 = (const float*)d_in[17], *cv3 = (const float*)d_in[18];
    const float* Wvm = (const float*)d_in[19], *bvm = (const float*)d_in[20];
    const float* Wvl = (const float*)d_in[21], *bvl = (const float*)d_in[22];
    const float* W1  = (const float*)d_in[23], *b1  = (const float*)d_in[24];
    const float* W2  = (const float*)d_in[25], *b2  = (const float*)d_in[26];
    const float* Wf  = (const float*)d_in[27], *bf  = (const float*)d_in[28];
    const float* D1  = (const float*)d_in[29], *d1  = (const float*)d_in[30];
    const float* D2  = (const float*)d_in[31], *d2  = (const float*)d_in[32];
    const float* D3  = (const float*)d_in[33], *d3  = (const float*)d_in[34];
    const int*   Ndata = (const int*)d_in[35];

    float* out = (float*)d_out;
    float* ws  = (float*)d_ws;

    // s-chain scratch lives in the (currently dead) Xrec region of d_out
    float* a1s = out + OS_A1S;
    float* a2s = out + OS_A2S;

    // transposes + lhood zero + mu/lv atomic-target zero
    prep_enc<<<459, 256, 0, stream>>>(Cs1, Cv1, Cs2, Cv2, Cs3, Cv3, ws);

    // ---- both encoders, merged (z = 0: s / frame0, z = 1: v / 10 frames) ----
    conv1_both<<<dim3(256, 2, 2), 256, 0, stream>>>(X,
        ws + TC_S1, cs1, a1s,
        ws + TC_V1, cv1, ws + WS_A1V);
    conv2_both<<<dim3(256, 2, 2), 256, 0, stream>>>(
        a1s, ws + TC_S2, cs2, a2s,
        ws + WS_A1V, ws + TC_V2, cv2, ws + WS_A2V);
    conv3fc_both<<<dim3(256, 2, 2), 256, 0, stream>>>(
        a2s, ws + TC_S3, cs3, Wsm, Wsl, ws + WS_S0MU, ws + WS_S0LV,
        ws + WS_A2V, ws + TC_V3, cv3, Wvm, Wvl, ws + WS_V0MU, ws + WS_V0LV);

    // ---- RK4 ODE (+ reparam prologue + klz) with compose blocks overlapped ----
    ode_kernel<<<369, 256, 0, stream>>>(W1, b1, W2, b2,
        ws + WS_S0MU, ws + WS_S0LV, ws + WS_V0MU, ws + WS_V0LV,
        bsm, bsl, bvm, bvl, eps_s0, eps_v0,
        Wf, bf, D1, d1, D2, D3, ws,
        out + OUT_QM, out + OUT_QLV, out + OUT_ZT, ws + WS_KLZ);

    // ---- fused decoder ----
    decoder5<<<5120, 256, 0, stream>>>(out + OUT_ZT, ws + WS_M1, ws + WS_C1,
                                       ws + WS_WT2, d2, ws + WS_WT3, d3,
                                       X, out + OUT_XREC, ws + WS_LHOOD);

    // ---- final scalars ----
    final2<<<1, 256, 0, stream>>>(ws + WS_LHOOD, ws + WS_KLZ, W1, W2, Ndata,
                                  out + OUT_SCAL);
}